// Round 1
// baseline (385.105 us; speedup 1.0000x reference)
//
#include <hip/hip_runtime.h>
#include <hip/hip_bf16.h>
#include <math.h>

// ---------------- GEMM: C[M,N] = A[M,K] @ B[K,N], f32 ----------------
#define BM 64
#define BN 64
#define BK 32

__global__ __launch_bounds__(256) void gemm_f32(const float* __restrict__ A,
                                                const float* __restrict__ B,
                                                float* __restrict__ C,
                                                int M, int N, int K) {
    __shared__ float As[BK][BM];   // transposed: As[k][m]
    __shared__ float Bs[BK][BN];
    int tid = threadIdx.x;
    int tx = tid & 15, ty = tid >> 4;
    int row0 = blockIdx.y * BM + ty * 4;
    int col0 = blockIdx.x * BN + tx * 4;
    float acc[4][4] = {};
    for (int k0 = 0; k0 < K; k0 += BK) {
        #pragma unroll
        for (int i = 0; i < 2; ++i) {
            int idx = tid + i * 256;          // 0..511
            int r = idx >> 3;                 // 0..63
            int c4 = (idx & 7) << 2;          // 0..28
            int gr = blockIdx.y * BM + r;
            float4 v = make_float4(0.f, 0.f, 0.f, 0.f);
            if (gr < M) v = *(const float4*)&A[(size_t)gr * K + k0 + c4];
            As[c4 + 0][r] = v.x; As[c4 + 1][r] = v.y;
            As[c4 + 2][r] = v.z; As[c4 + 3][r] = v.w;
        }
        #pragma unroll
        for (int i = 0; i < 2; ++i) {
            int idx = tid + i * 256;
            int r = idx >> 4;                 // 0..31
            int c4 = (idx & 15) << 2;         // 0..60
            float4 v = *(const float4*)&B[(size_t)(k0 + r) * N + blockIdx.x * BN + c4];
            *(float4*)&Bs[r][c4] = v;
        }
        __syncthreads();
        #pragma unroll
        for (int kk = 0; kk < BK; ++kk) {
            float a[4], b[4];
            #pragma unroll
            for (int i = 0; i < 4; ++i) a[i] = As[kk][ty * 4 + i];
            #pragma unroll
            for (int j = 0; j < 4; ++j) b[j] = Bs[kk][tx * 4 + j];
            #pragma unroll
            for (int i = 0; i < 4; ++i)
                #pragma unroll
                for (int j = 0; j < 4; ++j)
                    acc[i][j] += a[i] * b[j];
        }
        __syncthreads();
    }
    #pragma unroll
    for (int i = 0; i < 4; ++i) {
        int r = row0 + i;
        if (r < M) {
            float4 v = make_float4(acc[i][0], acc[i][1], acc[i][2], acc[i][3]);
            *(float4*)&C[(size_t)r * N + col0] = v;
        }
    }
}

// ---------------- CSR build ----------------
__global__ void count_edges(const int* __restrict__ ei, int* __restrict__ counts,
                            int E0, int n) {
    int e = blockIdx.x * blockDim.x + threadIdx.x;
    int Etot = E0 + n;
    if (e >= Etot) return;
    int dst = (e < E0) ? ei[E0 + e] : (e - E0);
    atomicAdd(&counts[dst], 1);
}

__global__ void scan_excl(const int* __restrict__ counts, int* __restrict__ offsets, int n) {
    __shared__ int sbuf[1024];
    __shared__ int running;
    int tid = threadIdx.x;
    if (tid == 0) running = 0;
    __syncthreads();
    for (int base = 0; base < n; base += 1024) {
        int i = base + tid;
        int v = (i < n) ? counts[i] : 0;
        sbuf[tid] = v;
        __syncthreads();
        for (int off = 1; off < 1024; off <<= 1) {
            int t = (tid >= off) ? sbuf[tid - off] : 0;
            __syncthreads();
            sbuf[tid] += t;
            __syncthreads();
        }
        int incl = sbuf[tid];
        int r = running;
        if (i < n) offsets[i] = r + incl - v;   // exclusive
        __syncthreads();
        if (tid == 0) running = r + sbuf[1023];
        __syncthreads();
    }
    if (tid == 0) offsets[n] = running;
}

__global__ void fill_edges(const int* __restrict__ ei, const int* __restrict__ offsets,
                           int* __restrict__ cursor, int* __restrict__ srcs,
                           int E0, int n) {
    int e = blockIdx.x * blockDim.x + threadIdx.x;
    int Etot = E0 + n;
    if (e >= Etot) return;
    int src, dst;
    if (e < E0) { src = ei[e]; dst = ei[E0 + e]; }
    else        { src = dst = e - E0; }
    int pos = offsets[dst] + atomicAdd(&cursor[dst], 1);
    srcs[pos] = src;
}

// ---------------- Layer-1 attention scores: es/ed [N,32] ----------------
__global__ void attn_scores1(const float* __restrict__ h, const float* __restrict__ asrc,
                             const float* __restrict__ adst, float* __restrict__ es,
                             float* __restrict__ ed, int n) {
    int idx = blockIdx.x * blockDim.x + threadIdx.x;
    if (idx >= n * 32) return;
    int node = idx >> 5, head = idx & 31;
    const float4* hp = (const float4*)(h + (size_t)node * 1024 + head * 32);
    const float4* ap = (const float4*)(asrc + head * 32);
    const float4* dp = (const float4*)(adst + head * 32);
    float s1 = 0.f, s2 = 0.f;
    #pragma unroll
    for (int c = 0; c < 8; ++c) {
        float4 hv = hp[c], av = ap[c], dv = dp[c];
        s1 += hv.x * av.x + hv.y * av.y + hv.z * av.z + hv.w * av.w;
        s2 += hv.x * dv.x + hv.y * dv.y + hv.z * dv.z + hv.w * dv.w;
    }
    es[idx] = s1;
    ed[idx] = s2;
}

// ---------------- Layer-1 aggregation: out = elu(softmax-agg + b1) ----------------
__global__ __launch_bounds__(256) void aggregate1(const float* __restrict__ h,
                                                  const float* __restrict__ es,
                                                  const float* __restrict__ ed,
                                                  const int* __restrict__ offsets,
                                                  const int* __restrict__ srcs,
                                                  const float* __restrict__ b1,
                                                  float* __restrict__ out, int n) {
    int node = blockIdx.x;
    int tid = threadIdx.x;          // 256
    int head = tid >> 3;            // 0..31
    int j = tid & 7;                // edge lane within head group
    int c4 = (tid & 7) * 4;         // channel quad
    __shared__ float sm[32], ss[32], sed[32];
    int beg = offsets[node], end = offsets[node + 1];
    if (tid < 32) sed[tid] = ed[node * 32 + tid];
    __syncthreads();
    float edh = sed[head];
    // pass 1: per-head max
    float m = -1e30f;
    for (int e = beg + j; e < end; e += 8) {
        int s = srcs[e];
        float ev = es[s * 32 + head] + edh;
        ev = ev > 0.f ? ev : 0.2f * ev;
        m = fmaxf(m, ev);
    }
    m = fmaxf(m, __shfl_xor(m, 1));
    m = fmaxf(m, __shfl_xor(m, 2));
    m = fmaxf(m, __shfl_xor(m, 4));
    // pass 1b: per-head sum of exp
    float ssum = 0.f;
    for (int e = beg + j; e < end; e += 8) {
        int s = srcs[e];
        float ev = es[s * 32 + head] + edh;
        ev = ev > 0.f ? ev : 0.2f * ev;
        ssum += __expf(ev - m);
    }
    ssum += __shfl_xor(ssum, 1);
    ssum += __shfl_xor(ssum, 2);
    ssum += __shfl_xor(ssum, 4);
    if (j == 0) { sm[head] = m; ss[head] = ssum; }
    __syncthreads();
    float m_h = sm[head];
    float s_h = ss[head] + 1e-16f;
    // pass 2: weighted gather-accumulate (each thread owns 4 channels of one head)
    float a0 = 0.f, a1 = 0.f, a2 = 0.f, a3 = 0.f;
    for (int e = beg; e < end; ++e) {
        int s = srcs[e];
        float ev = es[s * 32 + head] + edh;
        ev = ev > 0.f ? ev : 0.2f * ev;
        float alpha = __expf(ev - m_h) / s_h;
        float4 hv = *(const float4*)&h[(size_t)s * 1024 + head * 32 + c4];
        a0 += alpha * hv.x; a1 += alpha * hv.y;
        a2 += alpha * hv.z; a3 += alpha * hv.w;
    }
    int o = head * 32 + c4;
    float r0 = a0 + b1[o + 0];
    float r1 = a1 + b1[o + 1];
    float r2 = a2 + b1[o + 2];
    float r3 = a3 + b1[o + 3];
    // ELU
    r0 = r0 > 0.f ? r0 : expm1f(r0);
    r1 = r1 > 0.f ? r1 : expm1f(r1);
    r2 = r2 > 0.f ? r2 : expm1f(r2);
    r3 = r3 > 0.f ? r3 : expm1f(r3);
    *(float4*)&out[(size_t)node * 1024 + o] = make_float4(r0, r1, r2, r3);
}

// ---------------- Layer-2 attention scores: es2/ed2 [N] ----------------
__global__ void attn_scores2(const float* __restrict__ h2, const float* __restrict__ asrc,
                             const float* __restrict__ adst, float* __restrict__ es,
                             float* __restrict__ ed, int n) {
    int node = blockIdx.x * (blockDim.x >> 6) + (threadIdx.x >> 6);
    int lane = threadIdx.x & 63;
    if (node >= n) return;
    float v = h2[(size_t)node * 64 + lane];
    float s1 = v * asrc[lane];
    float s2 = v * adst[lane];
    #pragma unroll
    for (int o = 1; o < 64; o <<= 1) {
        s1 += __shfl_xor(s1, o);
        s2 += __shfl_xor(s2, o);
    }
    if (lane == 0) { es[node] = s1; ed[node] = s2; }
}

// ---------------- Layer-2 aggregation: d_out = softmax-agg + b2 ----------------
__global__ void aggregate2(const float* __restrict__ h2, const float* __restrict__ es,
                           const float* __restrict__ ed, const int* __restrict__ offsets,
                           const int* __restrict__ srcs, const float* __restrict__ b2,
                           float* __restrict__ out, int n) {
    int node = blockIdx.x * (blockDim.x >> 6) + (threadIdx.x >> 6);
    int lane = threadIdx.x & 63;
    if (node >= n) return;
    int beg = offsets[node], end = offsets[node + 1];
    float edv = ed[node];
    float m = -1e30f;
    for (int e = beg + lane; e < end; e += 64) {
        float ev = es[srcs[e]] + edv;
        ev = ev > 0.f ? ev : 0.2f * ev;
        m = fmaxf(m, ev);
    }
    #pragma unroll
    for (int o = 1; o < 64; o <<= 1) m = fmaxf(m, __shfl_xor(m, o));
    float ssum = 0.f;
    for (int e = beg + lane; e < end; e += 64) {
        float ev = es[srcs[e]] + edv;
        ev = ev > 0.f ? ev : 0.2f * ev;
        ssum += __expf(ev - m);
    }
    #pragma unroll
    for (int o = 1; o < 64; o <<= 1) ssum += __shfl_xor(ssum, o);
    ssum += 1e-16f;
    float acc = 0.f;
    for (int e = beg; e < end; ++e) {
        int s = srcs[e];
        float ev = es[s] + edv;
        ev = ev > 0.f ? ev : 0.2f * ev;
        float alpha = __expf(ev - m) / ssum;
        acc += alpha * h2[(size_t)s * 64 + lane];
    }
    out[(size_t)node * 64 + lane] = acc + b2[lane];
}

// ---------------- launch ----------------
extern "C" void kernel_launch(void* const* d_in, const int* in_sizes, int n_in,
                              void* d_out, int out_size, void* d_ws, size_t ws_size,
                              hipStream_t stream) {
    const float* x        = (const float*)d_in[0];
    const int*   ei       = (const int*)d_in[1];
    const float* W1       = (const float*)d_in[2];
    const float* att_src1 = (const float*)d_in[3];
    const float* att_dst1 = (const float*)d_in[4];
    const float* b1       = (const float*)d_in[5];
    const float* W2       = (const float*)d_in[6];
    const float* att_src2 = (const float*)d_in[7];
    const float* att_dst2 = (const float*)d_in[8];
    const float* b2       = (const float*)d_in[9];
    float* out = (float*)d_out;

    int n  = in_sizes[0] / 128;   // 20000
    int E0 = in_sizes[1] / 2;     // 160000
    int Etot = E0 + n;

    // workspace layout (floats)
    float* ws = (float*)d_ws;
    size_t off = 0;
    float* h1   = ws + off; off += (size_t)n * 1024;   // layer-1 linear out; reused as h2
    float* hact = ws + off; off += (size_t)n * 1024;   // elu(layer-1 out)
    float* es1  = ws + off; off += (size_t)n * 32;     // reused as es2
    float* ed1  = ws + off; off += (size_t)n * 32;     // reused as ed2
    int* counts  = (int*)(ws + off); off += n;
    int* cursor  = (int*)(ws + off); off += n;
    int* offsets = (int*)(ws + off); off += n + 8;
    int* srcs    = (int*)(ws + off); off += Etot;
    float* h2  = h1;
    float* es2 = es1;
    float* ed2 = ed1;

    // CSR build (by dst, includes self-loops)
    hipMemsetAsync(counts, 0, 2 * (size_t)n * sizeof(int), stream);  // counts+cursor
    count_edges<<<(Etot + 255) / 256, 256, 0, stream>>>(ei, counts, E0, n);
    scan_excl<<<1, 1024, 0, stream>>>(counts, offsets, n);
    fill_edges<<<(Etot + 255) / 256, 256, 0, stream>>>(ei, offsets, cursor, srcs, E0, n);

    // layer 1
    gemm_f32<<<dim3(1024 / BN, (n + BM - 1) / BM), 256, 0, stream>>>(x, W1, h1, n, 1024, 128);
    attn_scores1<<<(n * 32 + 255) / 256, 256, 0, stream>>>(h1, att_src1, att_dst1, es1, ed1, n);
    aggregate1<<<n, 256, 0, stream>>>(h1, es1, ed1, offsets, srcs, b1, hact, n);

    // layer 2
    gemm_f32<<<dim3(64 / BN, (n + BM - 1) / BM), 256, 0, stream>>>(hact, W2, h2, n, 64, 1024);
    attn_scores2<<<(n + 3) / 4, 256, 0, stream>>>(h2, att_src2, att_dst2, es2, ed2, n);
    aggregate2<<<(n + 3) / 4, 256, 0, stream>>>(h2, es2, ed2, offsets, srcs, b2, out, n);
}

// Round 2
// 369.670 us; speedup vs baseline: 1.0418x; 1.0418x over previous
//
#include <hip/hip_runtime.h>
#include <hip/hip_bf16.h>
#include <math.h>

__device__ inline float bf2f(unsigned short u) {
    union { float f; unsigned int i; } c; c.i = ((unsigned int)u) << 16; return c.f;
}
__device__ inline unsigned short f2bf(float f) {
    union { float f; unsigned int i; } c; c.f = f;
    unsigned int r = c.i + 0x7fffu + ((c.i >> 16) & 1u);
    return (unsigned short)(r >> 16);
}

// ---------------- GEMM: C[M,N] = A[M,K] @ B[K,N], f32 ----------------
#define BM 64
#define BN 64
#define BK 32

__global__ __launch_bounds__(256) void gemm_f32(const float* __restrict__ A,
                                                const float* __restrict__ B,
                                                float* __restrict__ C,
                                                int M, int N, int K) {
    __shared__ float As[BK][BM];   // transposed: As[k][m]
    __shared__ float Bs[BK][BN];
    int tid = threadIdx.x;
    int tx = tid & 15, ty = tid >> 4;
    int row0 = blockIdx.y * BM + ty * 4;
    int col0 = blockIdx.x * BN + tx * 4;
    float acc[4][4] = {};
    for (int k0 = 0; k0 < K; k0 += BK) {
        #pragma unroll
        for (int i = 0; i < 2; ++i) {
            int idx = tid + i * 256;          // 0..511
            int r = idx >> 3;                 // 0..63
            int c4 = (idx & 7) << 2;          // 0..28
            int gr = blockIdx.y * BM + r;
            float4 v = make_float4(0.f, 0.f, 0.f, 0.f);
            if (gr < M) v = *(const float4*)&A[(size_t)gr * K + k0 + c4];
            As[c4 + 0][r] = v.x; As[c4 + 1][r] = v.y;
            As[c4 + 2][r] = v.z; As[c4 + 3][r] = v.w;
        }
        #pragma unroll
        for (int i = 0; i < 2; ++i) {
            int idx = tid + i * 256;
            int r = idx >> 4;                 // 0..31
            int c4 = (idx & 15) << 2;         // 0..60
            float4 v = *(const float4*)&B[(size_t)(k0 + r) * N + blockIdx.x * BN + c4];
            *(float4*)&Bs[r][c4] = v;
        }
        __syncthreads();
        #pragma unroll
        for (int kk = 0; kk < BK; ++kk) {
            float a[4], b[4];
            #pragma unroll
            for (int i = 0; i < 4; ++i) a[i] = As[kk][ty * 4 + i];
            #pragma unroll
            for (int j = 0; j < 4; ++j) b[j] = Bs[kk][tx * 4 + j];
            #pragma unroll
            for (int i = 0; i < 4; ++i)
                #pragma unroll
                for (int j = 0; j < 4; ++j)
                    acc[i][j] += a[i] * b[j];
        }
        __syncthreads();
    }
    #pragma unroll
    for (int i = 0; i < 4; ++i) {
        int r = row0 + i;
        if (r < M) {
            float4 v = make_float4(acc[i][0], acc[i][1], acc[i][2], acc[i][3]);
            *(float4*)&C[(size_t)r * N + col0] = v;
        }
    }
}

// ---------------- CSR build ----------------
__global__ void count_edges(const int* __restrict__ ei, int* __restrict__ counts,
                            int E0, int n) {
    int e = blockIdx.x * blockDim.x + threadIdx.x;
    int Etot = E0 + n;
    if (e >= Etot) return;
    int dst = (e < E0) ? ei[E0 + e] : (e - E0);
    atomicAdd(&counts[dst], 1);
}

__global__ void scan_excl(const int* __restrict__ counts, int* __restrict__ offsets, int n) {
    __shared__ int sbuf[1024];
    __shared__ int running;
    int tid = threadIdx.x;
    if (tid == 0) running = 0;
    __syncthreads();
    for (int base = 0; base < n; base += 1024) {
        int i = base + tid;
        int v = (i < n) ? counts[i] : 0;
        sbuf[tid] = v;
        __syncthreads();
        for (int off = 1; off < 1024; off <<= 1) {
            int t = (tid >= off) ? sbuf[tid - off] : 0;
            __syncthreads();
            sbuf[tid] += t;
            __syncthreads();
        }
        int incl = sbuf[tid];
        int r = running;
        if (i < n) offsets[i] = r + incl - v;   // exclusive
        __syncthreads();
        if (tid == 0) running = r + sbuf[1023];
        __syncthreads();
    }
    if (tid == 0) offsets[n] = running;
}

__global__ void fill_edges(const int* __restrict__ ei, const int* __restrict__ offsets,
                           int* __restrict__ cursor, int* __restrict__ srcs,
                           int E0, int n) {
    int e = blockIdx.x * blockDim.x + threadIdx.x;
    int Etot = E0 + n;
    if (e >= Etot) return;
    int src, dst;
    if (e < E0) { src = ei[e]; dst = ei[E0 + e]; }
    else        { src = dst = e - E0; }
    int pos = offsets[dst] + atomicAdd(&cursor[dst], 1);
    srcs[pos] = src;
}

// ---------------- Layer-1 attention scores + bf16 copy of h ----------------
__global__ void attn_scores1(const float* __restrict__ h, const float* __restrict__ asrc,
                             const float* __restrict__ adst, float* __restrict__ es,
                             float* __restrict__ ed, unsigned short* __restrict__ hb,
                             int n) {
    int idx = blockIdx.x * blockDim.x + threadIdx.x;
    if (idx >= n * 32) return;
    int node = idx >> 5, head = idx & 31;
    size_t base = (size_t)node * 1024 + head * 32;
    const float4* hp = (const float4*)(h + base);
    const float4* ap = (const float4*)(asrc + head * 32);
    const float4* dp = (const float4*)(adst + head * 32);
    float s1 = 0.f, s2 = 0.f;
    #pragma unroll
    for (int c = 0; c < 8; ++c) {
        float4 hv = hp[c], av = ap[c], dv = dp[c];
        s1 += hv.x * av.x + hv.y * av.y + hv.z * av.z + hv.w * av.w;
        s2 += hv.x * dv.x + hv.y * dv.y + hv.z * dv.z + hv.w * dv.w;
        ushort4 pk;
        pk.x = f2bf(hv.x); pk.y = f2bf(hv.y); pk.z = f2bf(hv.z); pk.w = f2bf(hv.w);
        *(ushort4*)&hb[base + c * 4] = pk;
    }
    es[idx] = s1;
    ed[idx] = s2;
}

// ---------------- Layer-1 aggregation: out = elu(softmax-agg + b1) ----------------
__global__ __launch_bounds__(256) void aggregate1(const unsigned short* __restrict__ hb,
                                                  const float* __restrict__ es,
                                                  const float* __restrict__ ed,
                                                  const int* __restrict__ offsets,
                                                  const int* __restrict__ srcs,
                                                  const float* __restrict__ b1,
                                                  float* __restrict__ out, int n) {
    int node = blockIdx.x;
    int tid = threadIdx.x;          // 256
    int head = tid >> 3;            // 0..31
    int j = tid & 7;                // edge lane within head group
    int c4 = j * 4;                 // channel quad
    __shared__ float sm[32], ss[32], sed[32];
    __shared__ float salpha[32][8];   // [head][edge-in-chunk], 2-way-max banks
    __shared__ int ssrc[8];
    int beg = offsets[node], end = offsets[node + 1];
    if (tid < 32) sed[tid] = ed[node * 32 + tid];
    __syncthreads();
    float edh = sed[head];
    // pass 1: per-head max
    float m = -1e30f;
    for (int e = beg + j; e < end; e += 8) {
        int s = srcs[e];
        float ev = es[s * 32 + head] + edh;
        ev = ev > 0.f ? ev : 0.2f * ev;
        m = fmaxf(m, ev);
    }
    m = fmaxf(m, __shfl_xor(m, 1));
    m = fmaxf(m, __shfl_xor(m, 2));
    m = fmaxf(m, __shfl_xor(m, 4));
    // pass 1b: per-head sum of exp
    float ssum = 0.f;
    for (int e = beg + j; e < end; e += 8) {
        int s = srcs[e];
        float ev = es[s * 32 + head] + edh;
        ev = ev > 0.f ? ev : 0.2f * ev;
        ssum += __expf(ev - m);
    }
    ssum += __shfl_xor(ssum, 1);
    ssum += __shfl_xor(ssum, 2);
    ssum += __shfl_xor(ssum, 4);
    if (j == 0) { sm[head] = m; ss[head] = ssum; }
    __syncthreads();
    float m_h = sm[head];
    float sinv = 1.0f / (ss[head] + 1e-16f);
    // pass 2: chunks of 8 edges; alpha computed ONCE per (edge,head) into LDS
    float a0 = 0.f, a1 = 0.f, a2 = 0.f, a3 = 0.f;
    for (int c0 = beg; c0 < end; c0 += 8) {
        __syncthreads();
        int e = c0 + j;
        if (tid < 8) ssrc[tid] = (c0 + tid < end) ? srcs[c0 + tid] : 0;
        if (e < end) {
            int s = srcs[e];
            float ev = es[s * 32 + head] + edh;
            ev = ev > 0.f ? ev : 0.2f * ev;
            salpha[head][j] = __expf(ev - m_h) * sinv;
        }
        __syncthreads();
        int lim = min(8, end - c0);
        for (int jj = 0; jj < lim; ++jj) {
            int s = ssrc[jj];
            float alpha = salpha[head][jj];
            ushort4 hv = *(const ushort4*)&hb[(size_t)s * 1024 + head * 32 + c4];
            a0 += alpha * bf2f(hv.x); a1 += alpha * bf2f(hv.y);
            a2 += alpha * bf2f(hv.z); a3 += alpha * bf2f(hv.w);
        }
    }
    int o = head * 32 + c4;
    float r0 = a0 + b1[o + 0];
    float r1 = a1 + b1[o + 1];
    float r2 = a2 + b1[o + 2];
    float r3 = a3 + b1[o + 3];
    // ELU
    r0 = r0 > 0.f ? r0 : expm1f(r0);
    r1 = r1 > 0.f ? r1 : expm1f(r1);
    r2 = r2 > 0.f ? r2 : expm1f(r2);
    r3 = r3 > 0.f ? r3 : expm1f(r3);
    *(float4*)&out[(size_t)node * 1024 + o] = make_float4(r0, r1, r2, r3);
}

// ---------------- Layer-2 attention scores + bf16 copy of h2 ----------------
__global__ void attn_scores2(const float* __restrict__ h2, const float* __restrict__ asrc,
                             const float* __restrict__ adst, float* __restrict__ es,
                             float* __restrict__ ed, unsigned short* __restrict__ hb2,
                             int n) {
    int node = blockIdx.x * (blockDim.x >> 6) + (threadIdx.x >> 6);
    int lane = threadIdx.x & 63;
    if (node >= n) return;
    float v = h2[(size_t)node * 64 + lane];
    hb2[(size_t)node * 64 + lane] = f2bf(v);
    float s1 = v * asrc[lane];
    float s2 = v * adst[lane];
    #pragma unroll
    for (int o = 1; o < 64; o <<= 1) {
        s1 += __shfl_xor(s1, o);
        s2 += __shfl_xor(s2, o);
    }
    if (lane == 0) { es[node] = s1; ed[node] = s2; }
}

// ---------------- Layer-2 aggregation: d_out = softmax-agg + b2 ----------------
__global__ void aggregate2(const unsigned short* __restrict__ hb2,
                           const float* __restrict__ es,
                           const float* __restrict__ ed, const int* __restrict__ offsets,
                           const int* __restrict__ srcs, const float* __restrict__ b2,
                           float* __restrict__ out, int n) {
    int node = blockIdx.x * (blockDim.x >> 6) + (threadIdx.x >> 6);
    int lane = threadIdx.x & 63;
    if (node >= n) return;
    int beg = offsets[node], end = offsets[node + 1];
    float edv = ed[node];
    float m = -1e30f;
    for (int e = beg + lane; e < end; e += 64) {
        float ev = es[srcs[e]] + edv;
        ev = ev > 0.f ? ev : 0.2f * ev;
        m = fmaxf(m, ev);
    }
    #pragma unroll
    for (int o = 1; o < 64; o <<= 1) m = fmaxf(m, __shfl_xor(m, o));
    float ssum = 0.f;
    for (int e = beg + lane; e < end; e += 64) {
        float ev = es[srcs[e]] + edv;
        ev = ev > 0.f ? ev : 0.2f * ev;
        ssum += __expf(ev - m);
    }
    #pragma unroll
    for (int o = 1; o < 64; o <<= 1) ssum += __shfl_xor(ssum, o);
    float sinv = 1.0f / (ssum + 1e-16f);
    // chunked: each lane computes alpha for one edge, broadcast via shuffle
    float acc = 0.f;
    for (int c0 = beg; c0 < end; c0 += 64) {
        int e = c0 + lane;
        float alpha = 0.f; int s = 0;
        if (e < end) {
            s = srcs[e];
            float ev = es[s] + edv;
            ev = ev > 0.f ? ev : 0.2f * ev;
            alpha = __expf(ev - m) * sinv;
        }
        int lim = min(64, end - c0);
        for (int jj = 0; jj < lim; ++jj) {
            float a = __shfl(alpha, jj);
            int sj = __shfl(s, jj);
            acc += a * bf2f(hb2[(size_t)sj * 64 + lane]);
        }
    }
    out[(size_t)node * 64 + lane] = acc + b2[lane];
}

// ---------------- launch ----------------
extern "C" void kernel_launch(void* const* d_in, const int* in_sizes, int n_in,
                              void* d_out, int out_size, void* d_ws, size_t ws_size,
                              hipStream_t stream) {
    const float* x        = (const float*)d_in[0];
    const int*   ei       = (const int*)d_in[1];
    const float* W1       = (const float*)d_in[2];
    const float* att_src1 = (const float*)d_in[3];
    const float* att_dst1 = (const float*)d_in[4];
    const float* b1       = (const float*)d_in[5];
    const float* W2       = (const float*)d_in[6];
    const float* att_src2 = (const float*)d_in[7];
    const float* att_dst2 = (const float*)d_in[8];
    const float* b2       = (const float*)d_in[9];
    float* out = (float*)d_out;

    int n  = in_sizes[0] / 128;   // 20000
    int E0 = in_sizes[1] / 2;     // 160000
    int Etot = E0 + n;

    // workspace layout (floats)
    float* ws = (float*)d_ws;
    size_t off = 0;
    float* h1   = ws + off; off += (size_t)n * 1024;   // layer-1 linear out; reused as h2
    float* hact = ws + off; off += (size_t)n * 1024;   // elu(layer-1 out)
    unsigned short* hb1 = (unsigned short*)(ws + off); off += (size_t)n * 512;  // bf16 h1
    float* es1  = ws + off; off += (size_t)n * 32;     // reused as es2
    float* ed1  = ws + off; off += (size_t)n * 32;     // reused as ed2
    int* counts  = (int*)(ws + off); off += n;
    int* cursor  = (int*)(ws + off); off += n;
    int* offsets = (int*)(ws + off); off += n + 8;
    int* srcs    = (int*)(ws + off); off += Etot;
    unsigned short* hb2 = (unsigned short*)(ws + off); off += (size_t)n * 32;  // bf16 h2
    float* h2  = h1;
    float* es2 = es1;
    float* ed2 = ed1;

    // CSR build (by dst, includes self-loops)
    hipMemsetAsync(counts, 0, 2 * (size_t)n * sizeof(int), stream);  // counts+cursor
    count_edges<<<(Etot + 255) / 256, 256, 0, stream>>>(ei, counts, E0, n);
    scan_excl<<<1, 1024, 0, stream>>>(counts, offsets, n);
    fill_edges<<<(Etot + 255) / 256, 256, 0, stream>>>(ei, offsets, cursor, srcs, E0, n);

    // layer 1
    gemm_f32<<<dim3(1024 / BN, (n + BM - 1) / BM), 256, 0, stream>>>(x, W1, h1, n, 1024, 128);
    attn_scores1<<<(n * 32 + 255) / 256, 256, 0, stream>>>(h1, att_src1, att_dst1, es1, ed1, hb1, n);
    aggregate1<<<n, 256, 0, stream>>>(hb1, es1, ed1, offsets, srcs, b1, hact, n);

    // layer 2
    gemm_f32<<<dim3(64 / BN, (n + BM - 1) / BM), 256, 0, stream>>>(hact, W2, h2, n, 64, 1024);
    attn_scores2<<<(n + 3) / 4, 256, 0, stream>>>(h2, att_src2, att_dst2, es2, ed2, hb2, n);
    aggregate2<<<(n + 3) / 4, 256, 0, stream>>>(hb2, es2, ed2, offsets, srcs, b2, out, n);
}

// Round 3
// 285.392 us; speedup vs baseline: 1.3494x; 1.2953x over previous
//
#include <hip/hip_runtime.h>
#include <hip/hip_bf16.h>
#include <math.h>

typedef __attribute__((ext_vector_type(8))) short bf16x8;
typedef __attribute__((ext_vector_type(4))) float f32x4;
typedef __attribute__((ext_vector_type(8))) unsigned short u16x8;

__device__ inline float bf2f(unsigned short u) {
    union { float f; unsigned int i; } c; c.i = ((unsigned int)u) << 16; return c.f;
}
__device__ inline unsigned short f2bf(float f) {
    union { float f; unsigned int i; } c; c.f = f;
    unsigned int r = c.i + 0x7fffu + ((c.i >> 16) & 1u);
    return (unsigned short)(r >> 16);
}

// ---------------- casts ----------------
__global__ void cast_f32_bf16(const float* __restrict__ in, unsigned short* __restrict__ out,
                              int count4) {
    int i = blockIdx.x * blockDim.x + threadIdx.x;
    if (i >= count4) return;
    float4 v = *(const float4*)&in[(size_t)i * 4];
    ushort4 o;
    o.x = f2bf(v.x); o.y = f2bf(v.y); o.z = f2bf(v.z); o.w = f2bf(v.w);
    *(ushort4*)&out[(size_t)i * 4] = o;
}

// W [K][N] row-major f32 -> WT [N][K] bf16
__global__ void transpose_cast(const float* __restrict__ W, unsigned short* __restrict__ WT,
                               int K, int N) {
    int idx = blockIdx.x * blockDim.x + threadIdx.x;
    if (idx >= K * N) return;
    int nn = idx / K, kk = idx - nn * K;
    WT[idx] = f2bf(W[(size_t)kk * N + nn]);
}

// ---------------- MFMA GEMM: C[M,N](bf16) = A[M,K](bf16) @ BT[N,K](bf16)^T ----
// 256 threads = 4 waves (2x2), each wave 32x32 out, block tile 64x64.
// Fragments loaded directly from global (no LDS).
__global__ __launch_bounds__(256) void gemm_mfma(const unsigned short* __restrict__ A,
                                                 const unsigned short* __restrict__ BT,
                                                 unsigned short* __restrict__ C,
                                                 int M, int N, int K) {
    int tid = threadIdx.x;
    int wid = tid >> 6, lane = tid & 63;
    int wm = wid >> 1, wn = wid & 1;
    int m0 = blockIdx.x * 64 + wm * 32;
    int n0 = blockIdx.y * 64 + wn * 32;
    int lr = lane & 15;          // row (A) / col (B) within frag
    int lk = (lane >> 4) * 8;    // k offset within frag

    // A rows for frags i=0,1 (clamped for tail block)
    int ra0 = min(m0 + lr, M - 1);
    int ra1 = min(m0 + 16 + lr, M - 1);
    const unsigned short* pa0 = A + (size_t)ra0 * K + lk;
    const unsigned short* pa1 = A + (size_t)ra1 * K + lk;
    const unsigned short* pb0 = BT + (size_t)(n0 + lr) * K + lk;
    const unsigned short* pb1 = BT + (size_t)(n0 + 16 + lr) * K + lk;

    f32x4 acc00 = {0,0,0,0}, acc01 = {0,0,0,0}, acc10 = {0,0,0,0}, acc11 = {0,0,0,0};
    for (int k = 0; k < K; k += 64) {
        bf16x8 a0 = *(const bf16x8*)(pa0 + k);
        bf16x8 a1 = *(const bf16x8*)(pa1 + k);
        bf16x8 b0 = *(const bf16x8*)(pb0 + k);
        bf16x8 b1 = *(const bf16x8*)(pb1 + k);
        bf16x8 a0b = *(const bf16x8*)(pa0 + k + 32);
        bf16x8 a1b = *(const bf16x8*)(pa1 + k + 32);
        bf16x8 b0b = *(const bf16x8*)(pb0 + k + 32);
        bf16x8 b1b = *(const bf16x8*)(pb1 + k + 32);
        acc00 = __builtin_amdgcn_mfma_f32_16x16x32_bf16(a0, b0, acc00, 0, 0, 0);
        acc01 = __builtin_amdgcn_mfma_f32_16x16x32_bf16(a0, b1, acc01, 0, 0, 0);
        acc10 = __builtin_amdgcn_mfma_f32_16x16x32_bf16(a1, b0, acc10, 0, 0, 0);
        acc11 = __builtin_amdgcn_mfma_f32_16x16x32_bf16(a1, b1, acc11, 0, 0, 0);
        acc00 = __builtin_amdgcn_mfma_f32_16x16x32_bf16(a0b, b0b, acc00, 0, 0, 0);
        acc01 = __builtin_amdgcn_mfma_f32_16x16x32_bf16(a0b, b1b, acc01, 0, 0, 0);
        acc10 = __builtin_amdgcn_mfma_f32_16x16x32_bf16(a1b, b0b, acc10, 0, 0, 0);
        acc11 = __builtin_amdgcn_mfma_f32_16x16x32_bf16(a1b, b1b, acc11, 0, 0, 0);
    }
    // store: row = m_base + i*16 + (lane>>4)*4 + r, col = n_base + j*16 + (lane&15)
    int srow = (lane >> 4) * 4;
    #pragma unroll
    for (int r = 0; r < 4; ++r) {
        int r0 = m0 + srow + r, r1 = m0 + 16 + srow + r;
        if (r0 < M) {
            C[(size_t)r0 * N + n0 + lr]      = f2bf(acc00[r]);
            C[(size_t)r0 * N + n0 + 16 + lr] = f2bf(acc01[r]);
        }
        if (r1 < M) {
            C[(size_t)r1 * N + n0 + lr]      = f2bf(acc10[r]);
            C[(size_t)r1 * N + n0 + 16 + lr] = f2bf(acc11[r]);
        }
    }
}

// ---------------- CSR build ----------------
__global__ void count_edges(const int* __restrict__ ei, int* __restrict__ counts,
                            int E0, int n) {
    int e = blockIdx.x * blockDim.x + threadIdx.x;
    int Etot = E0 + n;
    if (e >= Etot) return;
    int dst = (e < E0) ? ei[E0 + e] : (e - E0);
    atomicAdd(&counts[dst], 1);
}

__global__ void scan_excl(const int* __restrict__ counts, int* __restrict__ offsets, int n) {
    __shared__ int sbuf[1024];
    __shared__ int running;
    int tid = threadIdx.x;
    if (tid == 0) running = 0;
    __syncthreads();
    for (int base = 0; base < n; base += 1024) {
        int i = base + tid;
        int v = (i < n) ? counts[i] : 0;
        sbuf[tid] = v;
        __syncthreads();
        for (int off = 1; off < 1024; off <<= 1) {
            int t = (tid >= off) ? sbuf[tid - off] : 0;
            __syncthreads();
            sbuf[tid] += t;
            __syncthreads();
        }
        int incl = sbuf[tid];
        int r = running;
        if (i < n) offsets[i] = r + incl - v;   // exclusive
        __syncthreads();
        if (tid == 0) running = r + sbuf[1023];
        __syncthreads();
    }
    if (tid == 0) offsets[n] = running;
}

__global__ void fill_edges(const int* __restrict__ ei, const int* __restrict__ offsets,
                           int* __restrict__ cursor, int* __restrict__ srcs,
                           int E0, int n) {
    int e = blockIdx.x * blockDim.x + threadIdx.x;
    int Etot = E0 + n;
    if (e >= Etot) return;
    int src, dst;
    if (e < E0) { src = ei[e]; dst = ei[E0 + e]; }
    else        { src = dst = e - E0; }
    int pos = offsets[dst] + atomicAdd(&cursor[dst], 1);
    srcs[pos] = src;
}

// ---------------- Layer-1 attention scores from bf16 h ----------------
__global__ void attn_scores1(const unsigned short* __restrict__ hb,
                             const float* __restrict__ asrc,
                             const float* __restrict__ adst,
                             float* __restrict__ es, float* __restrict__ ed, int n) {
    int idx = blockIdx.x * blockDim.x + threadIdx.x;
    if (idx >= n * 32) return;
    int head = idx & 31;
    size_t base = (size_t)idx * 32;
    const float4* ap = (const float4*)(asrc + head * 32);
    const float4* dp = (const float4*)(adst + head * 32);
    float s1 = 0.f, s2 = 0.f;
    #pragma unroll
    for (int c = 0; c < 4; ++c) {
        u16x8 hv = *(const u16x8*)&hb[base + c * 8];
        float4 a0 = ap[c * 2], a1 = ap[c * 2 + 1];
        float4 d0 = dp[c * 2], d1 = dp[c * 2 + 1];
        float h0 = bf2f(hv[0]), h1 = bf2f(hv[1]), h2 = bf2f(hv[2]), h3 = bf2f(hv[3]);
        float h4 = bf2f(hv[4]), h5 = bf2f(hv[5]), h6 = bf2f(hv[6]), h7 = bf2f(hv[7]);
        s1 += h0 * a0.x + h1 * a0.y + h2 * a0.z + h3 * a0.w
            + h4 * a1.x + h5 * a1.y + h6 * a1.z + h7 * a1.w;
        s2 += h0 * d0.x + h1 * d0.y + h2 * d0.z + h3 * d0.w
            + h4 * d1.x + h5 * d1.y + h6 * d1.z + h7 * d1.w;
    }
    es[idx] = s1;
    ed[idx] = s2;
}

// ---------------- Layer-1 aggregation: hact = elu(softmax-agg + b1), bf16 out ----
__global__ __launch_bounds__(256) void aggregate1(const unsigned short* __restrict__ hb,
                                                  const float* __restrict__ es,
                                                  const float* __restrict__ ed,
                                                  const int* __restrict__ offsets,
                                                  const int* __restrict__ srcs,
                                                  const float* __restrict__ b1,
                                                  unsigned short* __restrict__ out, int n) {
    int node = blockIdx.x;
    int tid = threadIdx.x;          // 256
    int head = tid >> 3;            // 0..31
    int j = tid & 7;                // edge lane within head group
    int c4 = j * 4;                 // channel quad
    __shared__ float sm[32], ss[32], sed[32];
    __shared__ float salpha[32][8];
    __shared__ int ssrc[8];
    int beg = offsets[node], end = offsets[node + 1];
    if (tid < 32) sed[tid] = ed[node * 32 + tid];
    __syncthreads();
    float edh = sed[head];
    float m = -1e30f;
    for (int e = beg + j; e < end; e += 8) {
        int s = srcs[e];
        float ev = es[s * 32 + head] + edh;
        ev = ev > 0.f ? ev : 0.2f * ev;
        m = fmaxf(m, ev);
    }
    m = fmaxf(m, __shfl_xor(m, 1));
    m = fmaxf(m, __shfl_xor(m, 2));
    m = fmaxf(m, __shfl_xor(m, 4));
    float ssum = 0.f;
    for (int e = beg + j; e < end; e += 8) {
        int s = srcs[e];
        float ev = es[s * 32 + head] + edh;
        ev = ev > 0.f ? ev : 0.2f * ev;
        ssum += __expf(ev - m);
    }
    ssum += __shfl_xor(ssum, 1);
    ssum += __shfl_xor(ssum, 2);
    ssum += __shfl_xor(ssum, 4);
    if (j == 0) { sm[head] = m; ss[head] = ssum; }
    __syncthreads();
    float m_h = sm[head];
    float sinv = 1.0f / (ss[head] + 1e-16f);
    float a0 = 0.f, a1 = 0.f, a2 = 0.f, a3 = 0.f;
    for (int c0 = beg; c0 < end; c0 += 8) {
        __syncthreads();
        int e = c0 + j;
        if (tid < 8) ssrc[tid] = (c0 + tid < end) ? srcs[c0 + tid] : 0;
        if (e < end) {
            int s = srcs[e];
            float ev = es[s * 32 + head] + edh;
            ev = ev > 0.f ? ev : 0.2f * ev;
            salpha[head][j] = __expf(ev - m_h) * sinv;
        }
        __syncthreads();
        int lim = min(8, end - c0);
        for (int jj = 0; jj < lim; ++jj) {
            int s = ssrc[jj];
            float alpha = salpha[head][jj];
            ushort4 hv = *(const ushort4*)&hb[(size_t)s * 1024 + head * 32 + c4];
            a0 += alpha * bf2f(hv.x); a1 += alpha * bf2f(hv.y);
            a2 += alpha * bf2f(hv.z); a3 += alpha * bf2f(hv.w);
        }
    }
    int o = head * 32 + c4;
    float r0 = a0 + b1[o + 0];
    float r1 = a1 + b1[o + 1];
    float r2 = a2 + b1[o + 2];
    float r3 = a3 + b1[o + 3];
    r0 = r0 > 0.f ? r0 : expm1f(r0);
    r1 = r1 > 0.f ? r1 : expm1f(r1);
    r2 = r2 > 0.f ? r2 : expm1f(r2);
    r3 = r3 > 0.f ? r3 : expm1f(r3);
    ushort4 o4;
    o4.x = f2bf(r0); o4.y = f2bf(r1); o4.z = f2bf(r2); o4.w = f2bf(r3);
    *(ushort4*)&out[(size_t)node * 1024 + o] = o4;
}

// ---------------- Layer-2 attention scores from bf16 h2 ----------------
__global__ void attn_scores2(const unsigned short* __restrict__ hb2,
                             const float* __restrict__ asrc,
                             const float* __restrict__ adst,
                             float* __restrict__ es, float* __restrict__ ed, int n) {
    int node = blockIdx.x * (blockDim.x >> 6) + (threadIdx.x >> 6);
    int lane = threadIdx.x & 63;
    if (node >= n) return;
    float v = bf2f(hb2[(size_t)node * 64 + lane]);
    float s1 = v * asrc[lane];
    float s2 = v * adst[lane];
    #pragma unroll
    for (int o = 1; o < 64; o <<= 1) {
        s1 += __shfl_xor(s1, o);
        s2 += __shfl_xor(s2, o);
    }
    if (lane == 0) { es[node] = s1; ed[node] = s2; }
}

// ---------------- Layer-2 aggregation: d_out = softmax-agg + b2 ----------------
__global__ void aggregate2(const unsigned short* __restrict__ hb2,
                           const float* __restrict__ es,
                           const float* __restrict__ ed, const int* __restrict__ offsets,
                           const int* __restrict__ srcs, const float* __restrict__ b2,
                           float* __restrict__ out, int n) {
    int node = blockIdx.x * (blockDim.x >> 6) + (threadIdx.x >> 6);
    int lane = threadIdx.x & 63;
    if (node >= n) return;
    int beg = offsets[node], end = offsets[node + 1];
    float edv = ed[node];
    float m = -1e30f;
    for (int e = beg + lane; e < end; e += 64) {
        float ev = es[srcs[e]] + edv;
        ev = ev > 0.f ? ev : 0.2f * ev;
        m = fmaxf(m, ev);
    }
    #pragma unroll
    for (int o = 1; o < 64; o <<= 1) m = fmaxf(m, __shfl_xor(m, o));
    float ssum = 0.f;
    for (int e = beg + lane; e < end; e += 64) {
        float ev = es[srcs[e]] + edv;
        ev = ev > 0.f ? ev : 0.2f * ev;
        ssum += __expf(ev - m);
    }
    #pragma unroll
    for (int o = 1; o < 64; o <<= 1) ssum += __shfl_xor(ssum, o);
    float sinv = 1.0f / (ssum + 1e-16f);
    float acc = 0.f;
    for (int c0 = beg; c0 < end; c0 += 64) {
        int e = c0 + lane;
        float alpha = 0.f; int s = 0;
        if (e < end) {
            s = srcs[e];
            float ev = es[s] + edv;
            ev = ev > 0.f ? ev : 0.2f * ev;
            alpha = __expf(ev - m) * sinv;
        }
        int lim = min(64, end - c0);
        for (int jj = 0; jj < lim; ++jj) {
            float a = __shfl(alpha, jj);
            int sj = __shfl(s, jj);
            acc += a * bf2f(hb2[(size_t)sj * 64 + lane]);
        }
    }
    out[(size_t)node * 64 + lane] = acc + b2[lane];
}

// ---------------- launch ----------------
extern "C" void kernel_launch(void* const* d_in, const int* in_sizes, int n_in,
                              void* d_out, int out_size, void* d_ws, size_t ws_size,
                              hipStream_t stream) {
    const float* x        = (const float*)d_in[0];
    const int*   ei       = (const int*)d_in[1];
    const float* W1       = (const float*)d_in[2];
    const float* att_src1 = (const float*)d_in[3];
    const float* att_dst1 = (const float*)d_in[4];
    const float* b1       = (const float*)d_in[5];
    const float* W2       = (const float*)d_in[6];
    const float* att_src2 = (const float*)d_in[7];
    const float* att_dst2 = (const float*)d_in[8];
    const float* b2       = (const float*)d_in[9];
    float* out = (float*)d_out;

    int n  = in_sizes[0] / 128;   // 20000
    int E0 = in_sizes[1] / 2;     // 160000
    int Etot = E0 + n;

    // workspace layout (floats; all chunks 16B-aligned)
    float* ws = (float*)d_ws;
    size_t off = 0;
    unsigned short* hb1 = (unsigned short*)(ws + off); off += (size_t)n * 512;  // bf16 h1 [n,1024]
    unsigned short* hact = (unsigned short*)(ws + off); off += (size_t)n * 512; // bf16 elu out
    unsigned short* hb2 = (unsigned short*)(ws + off); off += (size_t)n * 32;   // bf16 h2 [n,64]
    unsigned short* xb  = (unsigned short*)(ws + off); off += (size_t)n * 64;   // bf16 x [n,128]
    unsigned short* W1T = (unsigned short*)(ws + off); off += 1024 * 128 / 2;   // [1024,128]
    unsigned short* W2T = (unsigned short*)(ws + off); off += 64 * 1024 / 2;    // [64,1024]
    float* es1  = ws + off; off += (size_t)n * 32;
    float* ed1  = ws + off; off += (size_t)n * 32;
    int* counts  = (int*)(ws + off); off += n;
    int* cursor  = (int*)(ws + off); off += n;
    int* offsets = (int*)(ws + off); off += n + 8;
    int* srcs    = (int*)(ws + off); off += Etot;
    float* es2 = es1;
    float* ed2 = ed1;

    // casts
    cast_f32_bf16<<<(n * 128 / 4 + 255) / 256, 256, 0, stream>>>(x, xb, n * 128 / 4);
    transpose_cast<<<(128 * 1024 + 255) / 256, 256, 0, stream>>>(W1, W1T, 128, 1024);
    transpose_cast<<<(1024 * 64 + 255) / 256, 256, 0, stream>>>(W2, W2T, 1024, 64);

    // CSR build (by dst, includes self-loops)
    hipMemsetAsync(counts, 0, 2 * (size_t)n * sizeof(int), stream);  // counts+cursor
    count_edges<<<(Etot + 255) / 256, 256, 0, stream>>>(ei, counts, E0, n);
    scan_excl<<<1, 1024, 0, stream>>>(counts, offsets, n);
    fill_edges<<<(Etot + 255) / 256, 256, 0, stream>>>(ei, offsets, cursor, srcs, E0, n);

    // layer 1: h1 = x @ W1 (bf16 out)
    gemm_mfma<<<dim3((n + 63) / 64, 1024 / 64), 256, 0, stream>>>(xb, W1T, hb1, n, 1024, 128);
    attn_scores1<<<(n * 32 + 255) / 256, 256, 0, stream>>>(hb1, att_src1, att_dst1, es1, ed1, n);
    aggregate1<<<n, 256, 0, stream>>>(hb1, es1, ed1, offsets, srcs, b1, hact, n);

    // layer 2: h2 = hact @ W2 (bf16 out)
    gemm_mfma<<<dim3((n + 63) / 64, 64 / 64), 256, 0, stream>>>(hact, W2T, hb2, n, 64, 1024);
    attn_scores2<<<(n + 3) / 4, 256, 0, stream>>>(hb2, att_src2, att_dst2, es2, ed2, n);
    aggregate2<<<(n + 3) / 4, 256, 0, stream>>>(hb2, es2, ed2, offsets, srcs, b2, out, n);
}

// Round 4
// 283.947 us; speedup vs baseline: 1.3563x; 1.0051x over previous
//
#include <hip/hip_runtime.h>
#include <hip/hip_bf16.h>
#include <math.h>

typedef __attribute__((ext_vector_type(8))) short bf16x8;
typedef __attribute__((ext_vector_type(4))) float f32x4;
typedef __attribute__((ext_vector_type(8))) unsigned short u16x8;

__device__ inline float bf2f(unsigned short u) {
    union { float f; unsigned int i; } c; c.i = ((unsigned int)u) << 16; return c.f;
}
__device__ inline unsigned short f2bf(float f) {
    union { float f; unsigned int i; } c; c.f = f;
    unsigned int r = c.i + 0x7fffu + ((c.i >> 16) & 1u);
    return (unsigned short)(r >> 16);
}

// ---------------- casts ----------------
__global__ void cast_f32_bf16(const float* __restrict__ in, unsigned short* __restrict__ out,
                              int count4) {
    int i = blockIdx.x * blockDim.x + threadIdx.x;
    if (i >= count4) return;
    float4 v = *(const float4*)&in[(size_t)i * 4];
    ushort4 o;
    o.x = f2bf(v.x); o.y = f2bf(v.y); o.z = f2bf(v.z); o.w = f2bf(v.w);
    *(ushort4*)&out[(size_t)i * 4] = o;
}

// W [K][N] row-major f32 -> WT [N][K] bf16
__global__ void transpose_cast(const float* __restrict__ W, unsigned short* __restrict__ WT,
                               int K, int N) {
    int idx = blockIdx.x * blockDim.x + threadIdx.x;
    if (idx >= K * N) return;
    int nn = idx / K, kk = idx - nn * K;
    WT[idx] = f2bf(W[(size_t)kk * N + nn]);
}

// ---------------- MFMA GEMM: C[M,N](bf16) = A[M,K](bf16) @ BT[N,K](bf16)^T ----
__global__ __launch_bounds__(256) void gemm_mfma(const unsigned short* __restrict__ A,
                                                 const unsigned short* __restrict__ BT,
                                                 unsigned short* __restrict__ C,
                                                 int M, int N, int K) {
    int tid = threadIdx.x;
    int wid = tid >> 6, lane = tid & 63;
    int wm = wid >> 1, wn = wid & 1;
    int m0 = blockIdx.x * 64 + wm * 32;
    int n0 = blockIdx.y * 64 + wn * 32;
    int lr = lane & 15;
    int lk = (lane >> 4) * 8;

    int ra0 = min(m0 + lr, M - 1);
    int ra1 = min(m0 + 16 + lr, M - 1);
    const unsigned short* pa0 = A + (size_t)ra0 * K + lk;
    const unsigned short* pa1 = A + (size_t)ra1 * K + lk;
    const unsigned short* pb0 = BT + (size_t)(n0 + lr) * K + lk;
    const unsigned short* pb1 = BT + (size_t)(n0 + 16 + lr) * K + lk;

    f32x4 acc00 = {0,0,0,0}, acc01 = {0,0,0,0}, acc10 = {0,0,0,0}, acc11 = {0,0,0,0};
    for (int k = 0; k < K; k += 64) {
        bf16x8 a0 = *(const bf16x8*)(pa0 + k);
        bf16x8 a1 = *(const bf16x8*)(pa1 + k);
        bf16x8 b0 = *(const bf16x8*)(pb0 + k);
        bf16x8 b1 = *(const bf16x8*)(pb1 + k);
        bf16x8 a0b = *(const bf16x8*)(pa0 + k + 32);
        bf16x8 a1b = *(const bf16x8*)(pa1 + k + 32);
        bf16x8 b0b = *(const bf16x8*)(pb0 + k + 32);
        bf16x8 b1b = *(const bf16x8*)(pb1 + k + 32);
        acc00 = __builtin_amdgcn_mfma_f32_16x16x32_bf16(a0, b0, acc00, 0, 0, 0);
        acc01 = __builtin_amdgcn_mfma_f32_16x16x32_bf16(a0, b1, acc01, 0, 0, 0);
        acc10 = __builtin_amdgcn_mfma_f32_16x16x32_bf16(a1, b0, acc10, 0, 0, 0);
        acc11 = __builtin_amdgcn_mfma_f32_16x16x32_bf16(a1, b1, acc11, 0, 0, 0);
        acc00 = __builtin_amdgcn_mfma_f32_16x16x32_bf16(a0b, b0b, acc00, 0, 0, 0);
        acc01 = __builtin_amdgcn_mfma_f32_16x16x32_bf16(a0b, b1b, acc01, 0, 0, 0);
        acc10 = __builtin_amdgcn_mfma_f32_16x16x32_bf16(a1b, b0b, acc10, 0, 0, 0);
        acc11 = __builtin_amdgcn_mfma_f32_16x16x32_bf16(a1b, b1b, acc11, 0, 0, 0);
    }
    int srow = (lane >> 4) * 4;
    #pragma unroll
    for (int r = 0; r < 4; ++r) {
        int r0 = m0 + srow + r, r1 = m0 + 16 + srow + r;
        if (r0 < M) {
            C[(size_t)r0 * N + n0 + lr]      = f2bf(acc00[r]);
            C[(size_t)r0 * N + n0 + 16 + lr] = f2bf(acc01[r]);
        }
        if (r1 < M) {
            C[(size_t)r1 * N + n0 + lr]      = f2bf(acc10[r]);
            C[(size_t)r1 * N + n0 + 16 + lr] = f2bf(acc11[r]);
        }
    }
}

// ---------------- CSR build ----------------
__global__ void count_edges(const int* __restrict__ ei, int* __restrict__ counts,
                            int E0, int n) {
    int e = blockIdx.x * blockDim.x + threadIdx.x;
    int Etot = E0 + n;
    if (e >= Etot) return;
    int dst = (e < E0) ? ei[E0 + e] : (e - E0);
    atomicAdd(&counts[dst], 1);
}

__global__ void scan_excl(const int* __restrict__ counts, int* __restrict__ offsets, int n) {
    __shared__ int sbuf[1024];
    __shared__ int running;
    int tid = threadIdx.x;
    if (tid == 0) running = 0;
    __syncthreads();
    for (int base = 0; base < n; base += 1024) {
        int i = base + tid;
        int v = (i < n) ? counts[i] : 0;
        sbuf[tid] = v;
        __syncthreads();
        for (int off = 1; off < 1024; off <<= 1) {
            int t = (tid >= off) ? sbuf[tid - off] : 0;
            __syncthreads();
            sbuf[tid] += t;
            __syncthreads();
        }
        int incl = sbuf[tid];
        int r = running;
        if (i < n) offsets[i] = r + incl - v;
        __syncthreads();
        if (tid == 0) running = r + sbuf[1023];
        __syncthreads();
    }
    if (tid == 0) offsets[n] = running;
}

__global__ void fill_edges(const int* __restrict__ ei, const int* __restrict__ offsets,
                           int* __restrict__ cursor, int* __restrict__ srcs,
                           int E0, int n) {
    int e = blockIdx.x * blockDim.x + threadIdx.x;
    int Etot = E0 + n;
    if (e >= Etot) return;
    int src, dst;
    if (e < E0) { src = ei[e]; dst = ei[E0 + e]; }
    else        { src = dst = e - E0; }
    int pos = offsets[dst] + atomicAdd(&cursor[dst], 1);
    srcs[pos] = src;
}

// ---------------- Layer-1 attention scores from bf16 h ----------------
__global__ void attn_scores1(const unsigned short* __restrict__ hb,
                             const float* __restrict__ asrc,
                             const float* __restrict__ adst,
                             float* __restrict__ es, float* __restrict__ ed, int n) {
    int idx = blockIdx.x * blockDim.x + threadIdx.x;
    if (idx >= n * 32) return;
    int head = idx & 31;
    size_t base = (size_t)idx * 32;
    const float4* ap = (const float4*)(asrc + head * 32);
    const float4* dp = (const float4*)(adst + head * 32);
    float s1 = 0.f, s2 = 0.f;
    #pragma unroll
    for (int c = 0; c < 4; ++c) {
        u16x8 hv = *(const u16x8*)&hb[base + c * 8];
        float4 a0 = ap[c * 2], a1 = ap[c * 2 + 1];
        float4 d0 = dp[c * 2], d1 = dp[c * 2 + 1];
        float h0 = bf2f(hv[0]), h1 = bf2f(hv[1]), h2 = bf2f(hv[2]), h3 = bf2f(hv[3]);
        float h4 = bf2f(hv[4]), h5 = bf2f(hv[5]), h6 = bf2f(hv[6]), h7 = bf2f(hv[7]);
        s1 += h0 * a0.x + h1 * a0.y + h2 * a0.z + h3 * a0.w
            + h4 * a1.x + h5 * a1.y + h6 * a1.z + h7 * a1.w;
        s2 += h0 * d0.x + h1 * d0.y + h2 * d0.z + h3 * d0.w
            + h4 * d1.x + h5 * d1.y + h6 * d1.z + h7 * d1.w;
    }
    es[idx] = s1;
    ed[idx] = s2;
}

// ---------------- Layer-1 softmax stats + alpha precompute ----------------
// Block per node. Phase A (tid = head*8 + j): online max/sum over edges, shuffle
// reduce over j. Phase B (tid = j*32 + head): write alpha[e*32+head] coalesced.
__global__ __launch_bounds__(256) void stats1(const float* __restrict__ es,
                                              const float* __restrict__ ed,
                                              const int* __restrict__ offsets,
                                              const int* __restrict__ srcs,
                                              float* __restrict__ ealpha, int n) {
    int node = blockIdx.x;
    int tid = threadIdx.x;
    int head = tid >> 3, j = tid & 7;
    __shared__ float sm[32], ssinv[32], sed[32];
    int beg = offsets[node], end = offsets[node + 1];
    if (tid < 32) sed[tid] = ed[node * 32 + tid];
    __syncthreads();
    float edh = sed[head];
    // online max+sum
    float m = -1e30f, ssum = 0.f;
    for (int e = beg + j; e < end; e += 8) {
        int s = srcs[e];
        float ev = es[s * 32 + head] + edh;
        ev = ev > 0.f ? ev : 0.2f * ev;
        if (ev > m) { ssum = ssum * __expf(m - ev) + 1.f; m = ev; }
        else        { ssum += __expf(ev - m); }
    }
    #pragma unroll
    for (int o = 1; o < 8; o <<= 1) {
        float mo = __shfl_xor(m, o);
        float so = __shfl_xor(ssum, o);
        float mn = fmaxf(m, mo);
        ssum = ssum * __expf(m - mn) + so * __expf(mo - mn);
        m = mn;
    }
    if (j == 0) { sm[head] = m; ssinv[head] = 1.0f / (ssum + 1e-16f); }
    __syncthreads();
    // phase B: coalesced alpha write
    int h2 = tid & 31, j2 = tid >> 5;
    float m_h = sm[h2], si = ssinv[h2], ed2 = sed[h2];
    for (int e = beg + j2; e < end; e += 8) {
        int s = srcs[e];
        float ev = es[s * 32 + h2] + ed2;
        ev = ev > 0.f ? ev : 0.2f * ev;
        ealpha[(size_t)e * 32 + h2] = __expf(ev - m_h) * si;
    }
}

// ---------------- Layer-1 gather: hact = elu(sum alpha*h + b1), bf16 out ------
// Block per node, no barriers, no exp: pure load/FMA stream.
__global__ __launch_bounds__(256) void gather1(const unsigned short* __restrict__ hb,
                                               const float* __restrict__ ealpha,
                                               const int* __restrict__ offsets,
                                               const int* __restrict__ srcs,
                                               const float* __restrict__ b1,
                                               unsigned short* __restrict__ out, int n) {
    int node = blockIdx.x;
    int tid = threadIdx.x;
    int head = tid >> 3, c4 = (tid & 7) * 4;
    int beg = offsets[node], end = offsets[node + 1];
    int hoff = head * 32 + c4;
    float a0 = 0.f, a1 = 0.f, a2 = 0.f, a3 = 0.f;
    int e = beg;
    for (; e + 2 <= end; e += 2) {
        int s0 = srcs[e], s1 = srcs[e + 1];
        float al0 = ealpha[(size_t)e * 32 + head];
        float al1 = ealpha[(size_t)(e + 1) * 32 + head];
        ushort4 h0 = *(const ushort4*)&hb[(size_t)s0 * 1024 + hoff];
        ushort4 h1 = *(const ushort4*)&hb[(size_t)s1 * 1024 + hoff];
        a0 += al0 * bf2f(h0.x) + al1 * bf2f(h1.x);
        a1 += al0 * bf2f(h0.y) + al1 * bf2f(h1.y);
        a2 += al0 * bf2f(h0.z) + al1 * bf2f(h1.z);
        a3 += al0 * bf2f(h0.w) + al1 * bf2f(h1.w);
    }
    if (e < end) {
        int s0 = srcs[e];
        float al0 = ealpha[(size_t)e * 32 + head];
        ushort4 h0 = *(const ushort4*)&hb[(size_t)s0 * 1024 + hoff];
        a0 += al0 * bf2f(h0.x); a1 += al0 * bf2f(h0.y);
        a2 += al0 * bf2f(h0.z); a3 += al0 * bf2f(h0.w);
    }
    float r0 = a0 + b1[hoff + 0];
    float r1 = a1 + b1[hoff + 1];
    float r2 = a2 + b1[hoff + 2];
    float r3 = a3 + b1[hoff + 3];
    r0 = r0 > 0.f ? r0 : expm1f(r0);
    r1 = r1 > 0.f ? r1 : expm1f(r1);
    r2 = r2 > 0.f ? r2 : expm1f(r2);
    r3 = r3 > 0.f ? r3 : expm1f(r3);
    ushort4 o4;
    o4.x = f2bf(r0); o4.y = f2bf(r1); o4.z = f2bf(r2); o4.w = f2bf(r3);
    *(ushort4*)&out[(size_t)node * 1024 + hoff] = o4;
}

// ---------------- Layer-2 attention scores from bf16 h2 ----------------
__global__ void attn_scores2(const unsigned short* __restrict__ hb2,
                             const float* __restrict__ asrc,
                             const float* __restrict__ adst,
                             float* __restrict__ es, float* __restrict__ ed, int n) {
    int node = blockIdx.x * (blockDim.x >> 6) + (threadIdx.x >> 6);
    int lane = threadIdx.x & 63;
    if (node >= n) return;
    float v = bf2f(hb2[(size_t)node * 64 + lane]);
    float s1 = v * asrc[lane];
    float s2 = v * adst[lane];
    #pragma unroll
    for (int o = 1; o < 64; o <<= 1) {
        s1 += __shfl_xor(s1, o);
        s2 += __shfl_xor(s2, o);
    }
    if (lane == 0) { es[node] = s1; ed[node] = s2; }
}

// ---------------- Layer-2 softmax stats + alpha precompute (wave/node) -------
__global__ void stats2(const float* __restrict__ es, const float* __restrict__ ed,
                       const int* __restrict__ offsets, const int* __restrict__ srcs,
                       float* __restrict__ ealpha2, int n) {
    int node = blockIdx.x * (blockDim.x >> 6) + (threadIdx.x >> 6);
    int lane = threadIdx.x & 63;
    if (node >= n) return;
    int beg = offsets[node], end = offsets[node + 1];
    float edv = ed[node];
    float m = -1e30f, ssum = 0.f;
    for (int e = beg + lane; e < end; e += 64) {
        float ev = es[srcs[e]] + edv;
        ev = ev > 0.f ? ev : 0.2f * ev;
        if (ev > m) { ssum = ssum * __expf(m - ev) + 1.f; m = ev; }
        else        { ssum += __expf(ev - m); }
    }
    #pragma unroll
    for (int o = 1; o < 64; o <<= 1) {
        float mo = __shfl_xor(m, o);
        float so = __shfl_xor(ssum, o);
        float mn = fmaxf(m, mo);
        ssum = ssum * __expf(m - mn) + so * __expf(mo - mn);
        m = mn;
    }
    float sinv = 1.0f / (ssum + 1e-16f);
    for (int e = beg + lane; e < end; e += 64) {
        float ev = es[srcs[e]] + edv;
        ev = ev > 0.f ? ev : 0.2f * ev;
        ealpha2[e] = __expf(ev - m) * sinv;
    }
}

// ---------------- Layer-2 gather: d_out = sum alpha*h2 + b2 ----------------
__global__ void gather2(const unsigned short* __restrict__ hb2,
                        const float* __restrict__ ealpha2,
                        const int* __restrict__ offsets, const int* __restrict__ srcs,
                        const float* __restrict__ b2, float* __restrict__ out, int n) {
    int node = blockIdx.x * (blockDim.x >> 6) + (threadIdx.x >> 6);
    int lane = threadIdx.x & 63;
    if (node >= n) return;
    int beg = offsets[node], end = offsets[node + 1];
    float acc = 0.f;
    for (int c0 = beg; c0 < end; c0 += 64) {
        int e = c0 + lane;
        float alpha = 0.f; int s = 0;
        if (e < end) { s = srcs[e]; alpha = ealpha2[e]; }
        int lim = min(64, end - c0);
        for (int jj = 0; jj < lim; ++jj) {
            float a = __shfl(alpha, jj);
            int sj = __shfl(s, jj);
            acc += a * bf2f(hb2[(size_t)sj * 64 + lane]);
        }
    }
    out[(size_t)node * 64 + lane] = acc + b2[lane];
}

// ---------------- launch ----------------
extern "C" void kernel_launch(void* const* d_in, const int* in_sizes, int n_in,
                              void* d_out, int out_size, void* d_ws, size_t ws_size,
                              hipStream_t stream) {
    const float* x        = (const float*)d_in[0];
    const int*   ei       = (const int*)d_in[1];
    const float* W1       = (const float*)d_in[2];
    const float* att_src1 = (const float*)d_in[3];
    const float* att_dst1 = (const float*)d_in[4];
    const float* b1       = (const float*)d_in[5];
    const float* W2       = (const float*)d_in[6];
    const float* att_src2 = (const float*)d_in[7];
    const float* att_dst2 = (const float*)d_in[8];
    const float* b2       = (const float*)d_in[9];
    float* out = (float*)d_out;

    int n  = in_sizes[0] / 128;   // 20000
    int E0 = in_sizes[1] / 2;     // 160000
    int Etot = E0 + n;

    float* ws = (float*)d_ws;
    size_t off = 0;
    unsigned short* hb1 = (unsigned short*)(ws + off); off += (size_t)n * 512;
    unsigned short* hact = (unsigned short*)(ws + off); off += (size_t)n * 512;
    unsigned short* hb2 = (unsigned short*)(ws + off); off += (size_t)n * 32;
    unsigned short* xb  = (unsigned short*)(ws + off); off += (size_t)n * 64;
    unsigned short* W1T = (unsigned short*)(ws + off); off += 1024 * 128 / 2;
    unsigned short* W2T = (unsigned short*)(ws + off); off += 64 * 1024 / 2;
    float* es1  = ws + off; off += (size_t)n * 32;
    float* ed1  = ws + off; off += (size_t)n * 32;
    float* ealpha1 = ws + off; off += (size_t)Etot * 32;
    float* ealpha2 = ws + off; off += (size_t)Etot;
    int* counts  = (int*)(ws + off); off += n;
    int* cursor  = (int*)(ws + off); off += n;
    int* offsets = (int*)(ws + off); off += n + 8;
    int* srcs    = (int*)(ws + off); off += Etot;
    float* es2 = es1;
    float* ed2 = ed1;

    // casts
    cast_f32_bf16<<<(n * 128 / 4 + 255) / 256, 256, 0, stream>>>(x, xb, n * 128 / 4);
    transpose_cast<<<(128 * 1024 + 255) / 256, 256, 0, stream>>>(W1, W1T, 128, 1024);
    transpose_cast<<<(1024 * 64 + 255) / 256, 256, 0, stream>>>(W2, W2T, 1024, 64);

    // CSR build
    hipMemsetAsync(counts, 0, 2 * (size_t)n * sizeof(int), stream);
    count_edges<<<(Etot + 255) / 256, 256, 0, stream>>>(ei, counts, E0, n);
    scan_excl<<<1, 1024, 0, stream>>>(counts, offsets, n);
    fill_edges<<<(Etot + 255) / 256, 256, 0, stream>>>(ei, offsets, cursor, srcs, E0, n);

    // layer 1
    gemm_mfma<<<dim3((n + 63) / 64, 1024 / 64), 256, 0, stream>>>(xb, W1T, hb1, n, 1024, 128);
    attn_scores1<<<(n * 32 + 255) / 256, 256, 0, stream>>>(hb1, att_src1, att_dst1, es1, ed1, n);
    stats1<<<n, 256, 0, stream>>>(es1, ed1, offsets, srcs, ealpha1, n);
    gather1<<<n, 256, 0, stream>>>(hb1, ealpha1, offsets, srcs, b1, hact, n);

    // layer 2
    gemm_mfma<<<dim3((n + 63) / 64, 64 / 64), 256, 0, stream>>>(hact, W2T, hb2, n, 64, 1024);
    attn_scores2<<<(n + 3) / 4, 256, 0, stream>>>(hb2, att_src2, att_dst2, es2, ed2, n);
    stats2<<<(n + 3) / 4, 256, 0, stream>>>(es2, ed2, offsets, srcs, ealpha2, n);
    gather2<<<(n + 3) / 4, 256, 0, stream>>>(hb2, ealpha2, offsets, srcs, b2, out, n);
}

// Round 5
// 257.759 us; speedup vs baseline: 1.4940x; 1.1016x over previous
//
#include <hip/hip_runtime.h>
#include <hip/hip_bf16.h>
#include <math.h>

typedef __attribute__((ext_vector_type(8))) short bf16x8;
typedef __attribute__((ext_vector_type(4))) float f32x4;

__device__ inline float bf2f(unsigned short u) {
    union { float f; unsigned int i; } c; c.i = ((unsigned int)u) << 16; return c.f;
}
__device__ inline unsigned short f2bf(float f) {
    union { float f; unsigned int i; } c; c.f = f;
    unsigned int r = c.i + 0x7fffu + ((c.i >> 16) & 1u);
    return (unsigned short)(r >> 16);
}

// ---------------- casts ----------------
__global__ void cast_f32_bf16(const float* __restrict__ in, unsigned short* __restrict__ out,
                              int count4) {
    int i = blockIdx.x * blockDim.x + threadIdx.x;
    if (i >= count4) return;
    float4 v = *(const float4*)&in[(size_t)i * 4];
    ushort4 o;
    o.x = f2bf(v.x); o.y = f2bf(v.y); o.z = f2bf(v.z); o.w = f2bf(v.w);
    *(ushort4*)&out[(size_t)i * 4] = o;
}

// W [K][N] row-major f32 -> WT [N][K] bf16
__global__ void transpose_cast(const float* __restrict__ W, unsigned short* __restrict__ WT,
                               int K, int N) {
    int idx = blockIdx.x * blockDim.x + threadIdx.x;
    if (idx >= K * N) return;
    int nn = idx / K, kk = idx - nn * K;
    WT[idx] = f2bf(W[(size_t)kk * N + nn]);
}

// ---------------- MFMA GEMM (layer 1) + es/ed epilogue -------------------
// C[M,1024](bf16) = A[M,128] @ BT[1024,128]^T ; each wave owns 32 rows x 32 cols
// = exactly one head's channel block -> reduce acc*asrc over 16 lanes for es/ed.
__global__ __launch_bounds__(256) void gemm_mfma_attn(const unsigned short* __restrict__ A,
                                                      const unsigned short* __restrict__ BT,
                                                      unsigned short* __restrict__ C,
                                                      const float* __restrict__ asrc,
                                                      const float* __restrict__ adst,
                                                      float* __restrict__ es,
                                                      float* __restrict__ ed,
                                                      int M, int N, int K) {
    int tid = threadIdx.x;
    int wid = tid >> 6, lane = tid & 63;
    int wm = wid >> 1, wn = wid & 1;
    int m0 = blockIdx.x * 64 + wm * 32;
    int n0 = blockIdx.y * 64 + wn * 32;
    int lr = lane & 15;
    int q  = lane >> 4;
    int lk = q * 8;

    int ra0 = min(m0 + lr, M - 1);
    int ra1 = min(m0 + 16 + lr, M - 1);
    const unsigned short* pa0 = A + (size_t)ra0 * K + lk;
    const unsigned short* pa1 = A + (size_t)ra1 * K + lk;
    const unsigned short* pb0 = BT + (size_t)(n0 + lr) * K + lk;
    const unsigned short* pb1 = BT + (size_t)(n0 + 16 + lr) * K + lk;

    f32x4 acc00 = {0,0,0,0}, acc01 = {0,0,0,0}, acc10 = {0,0,0,0}, acc11 = {0,0,0,0};
    for (int k = 0; k < K; k += 64) {
        bf16x8 a0 = *(const bf16x8*)(pa0 + k);
        bf16x8 a1 = *(const bf16x8*)(pa1 + k);
        bf16x8 b0 = *(const bf16x8*)(pb0 + k);
        bf16x8 b1 = *(const bf16x8*)(pb1 + k);
        bf16x8 a0b = *(const bf16x8*)(pa0 + k + 32);
        bf16x8 a1b = *(const bf16x8*)(pa1 + k + 32);
        bf16x8 b0b = *(const bf16x8*)(pb0 + k + 32);
        bf16x8 b1b = *(const bf16x8*)(pb1 + k + 32);
        acc00 = __builtin_amdgcn_mfma_f32_16x16x32_bf16(a0, b0, acc00, 0, 0, 0);
        acc01 = __builtin_amdgcn_mfma_f32_16x16x32_bf16(a0, b1, acc01, 0, 0, 0);
        acc10 = __builtin_amdgcn_mfma_f32_16x16x32_bf16(a1, b0, acc10, 0, 0, 0);
        acc11 = __builtin_amdgcn_mfma_f32_16x16x32_bf16(a1, b1, acc11, 0, 0, 0);
        acc00 = __builtin_amdgcn_mfma_f32_16x16x32_bf16(a0b, b0b, acc00, 0, 0, 0);
        acc01 = __builtin_amdgcn_mfma_f32_16x16x32_bf16(a0b, b1b, acc01, 0, 0, 0);
        acc10 = __builtin_amdgcn_mfma_f32_16x16x32_bf16(a1b, b0b, acc10, 0, 0, 0);
        acc11 = __builtin_amdgcn_mfma_f32_16x16x32_bf16(a1b, b1b, acc11, 0, 0, 0);
    }
    // C store (bf16)
    int srow = q * 4;
    #pragma unroll
    for (int r = 0; r < 4; ++r) {
        int r0 = m0 + srow + r, r1 = m0 + 16 + srow + r;
        if (r0 < M) {
            C[(size_t)r0 * N + n0 + lr]      = f2bf(acc00[r]);
            C[(size_t)r0 * N + n0 + 16 + lr] = f2bf(acc01[r]);
        }
        if (r1 < M) {
            C[(size_t)r1 * N + n0 + lr]      = f2bf(acc10[r]);
            C[(size_t)r1 * N + n0 + 16 + lr] = f2bf(acc11[r]);
        }
    }
    // es/ed epilogue: head = this wave's 32-col block
    int head = blockIdx.y * 2 + wn;
    float as_lo = asrc[head * 32 + lr], as_hi = asrc[head * 32 + 16 + lr];
    float ad_lo = adst[head * 32 + lr], ad_hi = adst[head * 32 + 16 + lr];
    #pragma unroll
    for (int X = 0; X < 2; ++X) {
        f32x4 ac0 = X ? acc10 : acc00;
        f32x4 ac1 = X ? acc11 : acc01;
        #pragma unroll
        for (int r = 0; r < 4; ++r) {
            float ps = ac0[r] * as_lo + ac1[r] * as_hi;
            float pd = ac0[r] * ad_lo + ac1[r] * ad_hi;
            #pragma unroll
            for (int msk = 1; msk < 16; msk <<= 1) {
                ps += __shfl_xor(ps, msk);
                pd += __shfl_xor(pd, msk);
            }
            int row = m0 + X * 16 + q * 4 + r;
            if (lr == 0 && row < M) {
                es[row * 32 + head] = ps;
                ed[row * 32 + head] = pd;
            }
        }
    }
}

// ---------------- MFMA GEMM plain (layer 2) ----------------
__global__ __launch_bounds__(256) void gemm_mfma(const unsigned short* __restrict__ A,
                                                 const unsigned short* __restrict__ BT,
                                                 unsigned short* __restrict__ C,
                                                 int M, int N, int K) {
    int tid = threadIdx.x;
    int wid = tid >> 6, lane = tid & 63;
    int wm = wid >> 1, wn = wid & 1;
    int m0 = blockIdx.x * 64 + wm * 32;
    int n0 = blockIdx.y * 64 + wn * 32;
    int lr = lane & 15;
    int lk = (lane >> 4) * 8;

    int ra0 = min(m0 + lr, M - 1);
    int ra1 = min(m0 + 16 + lr, M - 1);
    const unsigned short* pa0 = A + (size_t)ra0 * K + lk;
    const unsigned short* pa1 = A + (size_t)ra1 * K + lk;
    const unsigned short* pb0 = BT + (size_t)(n0 + lr) * K + lk;
    const unsigned short* pb1 = BT + (size_t)(n0 + 16 + lr) * K + lk;

    f32x4 acc00 = {0,0,0,0}, acc01 = {0,0,0,0}, acc10 = {0,0,0,0}, acc11 = {0,0,0,0};
    for (int k = 0; k < K; k += 64) {
        bf16x8 a0 = *(const bf16x8*)(pa0 + k);
        bf16x8 a1 = *(const bf16x8*)(pa1 + k);
        bf16x8 b0 = *(const bf16x8*)(pb0 + k);
        bf16x8 b1 = *(const bf16x8*)(pb1 + k);
        bf16x8 a0b = *(const bf16x8*)(pa0 + k + 32);
        bf16x8 a1b = *(const bf16x8*)(pa1 + k + 32);
        bf16x8 b0b = *(const bf16x8*)(pb0 + k + 32);
        bf16x8 b1b = *(const bf16x8*)(pb1 + k + 32);
        acc00 = __builtin_amdgcn_mfma_f32_16x16x32_bf16(a0, b0, acc00, 0, 0, 0);
        acc01 = __builtin_amdgcn_mfma_f32_16x16x32_bf16(a0, b1, acc01, 0, 0, 0);
        acc10 = __builtin_amdgcn_mfma_f32_16x16x32_bf16(a1, b0, acc10, 0, 0, 0);
        acc11 = __builtin_amdgcn_mfma_f32_16x16x32_bf16(a1, b1, acc11, 0, 0, 0);
        acc00 = __builtin_amdgcn_mfma_f32_16x16x32_bf16(a0b, b0b, acc00, 0, 0, 0);
        acc01 = __builtin_amdgcn_mfma_f32_16x16x32_bf16(a0b, b1b, acc01, 0, 0, 0);
        acc10 = __builtin_amdgcn_mfma_f32_16x16x32_bf16(a1b, b0b, acc10, 0, 0, 0);
        acc11 = __builtin_amdgcn_mfma_f32_16x16x32_bf16(a1b, b1b, acc11, 0, 0, 0);
    }
    int srow = (lane >> 4) * 4;
    #pragma unroll
    for (int r = 0; r < 4; ++r) {
        int r0 = m0 + srow + r, r1 = m0 + 16 + srow + r;
        if (r0 < M) {
            C[(size_t)r0 * N + n0 + lr]      = f2bf(acc00[r]);
            C[(size_t)r0 * N + n0 + 16 + lr] = f2bf(acc01[r]);
        }
        if (r1 < M) {
            C[(size_t)r1 * N + n0 + lr]      = f2bf(acc10[r]);
            C[(size_t)r1 * N + n0 + 16 + lr] = f2bf(acc11[r]);
        }
    }
}

// ---------------- CSR build ----------------
__global__ void count_edges(const int* __restrict__ ei, int* __restrict__ counts,
                            int E0, int n) {
    int e = blockIdx.x * blockDim.x + threadIdx.x;
    int Etot = E0 + n;
    if (e >= Etot) return;
    int dst = (e < E0) ? ei[E0 + e] : (e - E0);
    atomicAdd(&counts[dst], 1);
}

__global__ void scan_excl(const int* __restrict__ counts, int* __restrict__ offsets, int n) {
    __shared__ int sbuf[1024];
    __shared__ int running;
    int tid = threadIdx.x;
    if (tid == 0) running = 0;
    __syncthreads();
    for (int base = 0; base < n; base += 1024) {
        int i = base + tid;
        int v = (i < n) ? counts[i] : 0;
        sbuf[tid] = v;
        __syncthreads();
        for (int off = 1; off < 1024; off <<= 1) {
            int t = (tid >= off) ? sbuf[tid - off] : 0;
            __syncthreads();
            sbuf[tid] += t;
            __syncthreads();
        }
        int incl = sbuf[tid];
        int r = running;
        if (i < n) offsets[i] = r + incl - v;
        __syncthreads();
        if (tid == 0) running = r + sbuf[1023];
        __syncthreads();
    }
    if (tid == 0) offsets[n] = running;
}

__global__ void fill_edges(const int* __restrict__ ei, const int* __restrict__ offsets,
                           int* __restrict__ cursor, int* __restrict__ srcs,
                           int E0, int n) {
    int e = blockIdx.x * blockDim.x + threadIdx.x;
    int Etot = E0 + n;
    if (e >= Etot) return;
    int src, dst;
    if (e < E0) { src = ei[e]; dst = ei[E0 + e]; }
    else        { src = dst = e - E0; }
    int pos = offsets[dst] + atomicAdd(&cursor[dst], 1);
    srcs[pos] = src;
}

// ---------------- Layer-1 stats: single sweep, no max, deferred norm -------
// t = exp(leaky(es[src]+ed[dst])) written unnormalized; sinv = 1/sum(t).
// Layout (j2=tid>>5, h2=tid&31): 32 lanes read one 128B es row -> coalesced.
__global__ __launch_bounds__(256) void stats1(const float* __restrict__ es,
                                              const float* __restrict__ ed,
                                              const int* __restrict__ offsets,
                                              const int* __restrict__ srcs,
                                              float* __restrict__ et,
                                              float* __restrict__ sinv, int n) {
    int node = blockIdx.x;
    int tid = threadIdx.x;
    int h2 = tid & 31, j2 = tid >> 5;
    __shared__ float sed[32];
    __shared__ float red[4][32];
    int beg = offsets[node], end = offsets[node + 1];
    if (tid < 32) sed[tid] = ed[node * 32 + tid];
    __syncthreads();
    float edh = sed[h2];
    float ssum = 0.f;
    for (int e = beg + j2; e < end; e += 8) {
        int s = srcs[e];
        float ev = es[s * 32 + h2] + edh;
        ev = ev > 0.f ? ev : 0.2f * ev;
        float t = __expf(ev);
        et[(size_t)e * 32 + h2] = t;
        ssum += t;
    }
    ssum += __shfl_xor(ssum, 32);                 // combine j2 pair within wave
    int w = tid >> 6;
    if ((tid & 63) < 32) red[w][h2] = ssum;
    __syncthreads();
    if (tid < 32) {
        float s = red[0][tid] + red[1][tid] + red[2][tid] + red[3][tid];
        sinv[node * 32 + tid] = 1.0f / (s + 1e-16f);
    }
}

// ---------------- Layer-1 gather: hact = elu(sinv * sum t*h + b1) ----------
__global__ __launch_bounds__(256) void gather1(const unsigned short* __restrict__ hb,
                                               const float* __restrict__ et,
                                               const float* __restrict__ sinv,
                                               const int* __restrict__ offsets,
                                               const int* __restrict__ srcs,
                                               const float* __restrict__ b1,
                                               unsigned short* __restrict__ out, int n) {
    int node = blockIdx.x;
    int tid = threadIdx.x;
    int head = tid >> 3, c4 = (tid & 7) * 4;
    int beg = offsets[node], end = offsets[node + 1];
    int hoff = head * 32 + c4;
    float a0 = 0.f, a1 = 0.f, a2 = 0.f, a3 = 0.f;
    int e = beg;
    for (; e + 4 <= end; e += 4) {
        int s0 = srcs[e], s1 = srcs[e + 1], s2 = srcs[e + 2], s3 = srcs[e + 3];
        float t0 = et[(size_t)e * 32 + head];
        float t1 = et[(size_t)(e + 1) * 32 + head];
        float t2 = et[(size_t)(e + 2) * 32 + head];
        float t3 = et[(size_t)(e + 3) * 32 + head];
        ushort4 h0 = *(const ushort4*)&hb[(size_t)s0 * 1024 + hoff];
        ushort4 h1 = *(const ushort4*)&hb[(size_t)s1 * 1024 + hoff];
        ushort4 h2 = *(const ushort4*)&hb[(size_t)s2 * 1024 + hoff];
        ushort4 h3 = *(const ushort4*)&hb[(size_t)s3 * 1024 + hoff];
        a0 += t0 * bf2f(h0.x) + t1 * bf2f(h1.x) + t2 * bf2f(h2.x) + t3 * bf2f(h3.x);
        a1 += t0 * bf2f(h0.y) + t1 * bf2f(h1.y) + t2 * bf2f(h2.y) + t3 * bf2f(h3.y);
        a2 += t0 * bf2f(h0.z) + t1 * bf2f(h1.z) + t2 * bf2f(h2.z) + t3 * bf2f(h3.z);
        a3 += t0 * bf2f(h0.w) + t1 * bf2f(h1.w) + t2 * bf2f(h2.w) + t3 * bf2f(h3.w);
    }
    for (; e < end; ++e) {
        int s0 = srcs[e];
        float t0 = et[(size_t)e * 32 + head];
        ushort4 h0 = *(const ushort4*)&hb[(size_t)s0 * 1024 + hoff];
        a0 += t0 * bf2f(h0.x); a1 += t0 * bf2f(h0.y);
        a2 += t0 * bf2f(h0.z); a3 += t0 * bf2f(h0.w);
    }
    float si = sinv[node * 32 + head];
    float r0 = a0 * si + b1[hoff + 0];
    float r1 = a1 * si + b1[hoff + 1];
    float r2 = a2 * si + b1[hoff + 2];
    float r3 = a3 * si + b1[hoff + 3];
    r0 = r0 > 0.f ? r0 : expm1f(r0);
    r1 = r1 > 0.f ? r1 : expm1f(r1);
    r2 = r2 > 0.f ? r2 : expm1f(r2);
    r3 = r3 > 0.f ? r3 : expm1f(r3);
    ushort4 o4;
    o4.x = f2bf(r0); o4.y = f2bf(r1); o4.z = f2bf(r2); o4.w = f2bf(r3);
    *(ushort4*)&out[(size_t)node * 1024 + hoff] = o4;
}

// ---------------- Layer-2 attention scores from bf16 h2 ----------------
__global__ void attn_scores2(const unsigned short* __restrict__ hb2,
                             const float* __restrict__ asrc,
                             const float* __restrict__ adst,
                             float* __restrict__ es, float* __restrict__ ed, int n) {
    int node = blockIdx.x * (blockDim.x >> 6) + (threadIdx.x >> 6);
    int lane = threadIdx.x & 63;
    if (node >= n) return;
    float v = bf2f(hb2[(size_t)node * 64 + lane]);
    float s1 = v * asrc[lane];
    float s2 = v * adst[lane];
    #pragma unroll
    for (int o = 1; o < 64; o <<= 1) {
        s1 += __shfl_xor(s1, o);
        s2 += __shfl_xor(s2, o);
    }
    if (lane == 0) { es[node] = s1; ed[node] = s2; }
}

// ---------------- Layer-2 stats: single sweep, no max ----------------
__global__ void stats2(const float* __restrict__ es, const float* __restrict__ ed,
                       const int* __restrict__ offsets, const int* __restrict__ srcs,
                       float* __restrict__ et2, float* __restrict__ sinv2, int n) {
    int node = blockIdx.x * (blockDim.x >> 6) + (threadIdx.x >> 6);
    int lane = threadIdx.x & 63;
    if (node >= n) return;
    int beg = offsets[node], end = offsets[node + 1];
    float edv = ed[node];
    float ssum = 0.f;
    for (int e = beg + lane; e < end; e += 64) {
        float ev = es[srcs[e]] + edv;
        ev = ev > 0.f ? ev : 0.2f * ev;
        float t = __expf(ev);
        et2[e] = t;
        ssum += t;
    }
    #pragma unroll
    for (int o = 1; o < 64; o <<= 1) ssum += __shfl_xor(ssum, o);
    if (lane == 0) sinv2[node] = 1.0f / (ssum + 1e-16f);
}

// ---------------- Layer-2 gather: d_out = sinv2 * sum t*h2 + b2 -------------
__global__ void gather2(const unsigned short* __restrict__ hb2,
                        const float* __restrict__ et2,
                        const float* __restrict__ sinv2,
                        const int* __restrict__ offsets, const int* __restrict__ srcs,
                        const float* __restrict__ b2, float* __restrict__ out, int n) {
    int node = blockIdx.x * (blockDim.x >> 6) + (threadIdx.x >> 6);
    int lane = threadIdx.x & 63;
    if (node >= n) return;
    int beg = offsets[node], end = offsets[node + 1];
    float acc = 0.f;
    for (int c0 = beg; c0 < end; c0 += 64) {
        int e = c0 + lane;
        float t = 0.f; int s = 0;
        if (e < end) { s = srcs[e]; t = et2[e]; }
        int lim = min(64, end - c0);
        for (int jj = 0; jj < lim; ++jj) {
            float a = __shfl(t, jj);
            int sj = __shfl(s, jj);
            acc += a * bf2f(hb2[(size_t)sj * 64 + lane]);
        }
    }
    out[(size_t)node * 64 + lane] = acc * sinv2[node] + b2[lane];
}

// ---------------- launch ----------------
extern "C" void kernel_launch(void* const* d_in, const int* in_sizes, int n_in,
                              void* d_out, int out_size, void* d_ws, size_t ws_size,
                              hipStream_t stream) {
    const float* x        = (const float*)d_in[0];
    const int*   ei       = (const int*)d_in[1];
    const float* W1       = (const float*)d_in[2];
    const float* att_src1 = (const float*)d_in[3];
    const float* att_dst1 = (const float*)d_in[4];
    const float* b1       = (const float*)d_in[5];
    const float* W2       = (const float*)d_in[6];
    const float* att_src2 = (const float*)d_in[7];
    const float* att_dst2 = (const float*)d_in[8];
    const float* b2       = (const float*)d_in[9];
    float* out = (float*)d_out;

    int n  = in_sizes[0] / 128;   // 20000
    int E0 = in_sizes[1] / 2;     // 160000
    int Etot = E0 + n;

    float* ws = (float*)d_ws;
    size_t off = 0;
    unsigned short* hb1 = (unsigned short*)(ws + off); off += (size_t)n * 512;
    unsigned short* hact = (unsigned short*)(ws + off); off += (size_t)n * 512;
    unsigned short* hb2 = (unsigned short*)(ws + off); off += (size_t)n * 32;
    unsigned short* xb  = (unsigned short*)(ws + off); off += (size_t)n * 64;
    unsigned short* W1T = (unsigned short*)(ws + off); off += 1024 * 128 / 2;
    unsigned short* W2T = (unsigned short*)(ws + off); off += 64 * 1024 / 2;
    float* es1  = ws + off; off += (size_t)n * 32;
    float* ed1  = ws + off; off += (size_t)n * 32;
    float* et1  = ws + off; off += (size_t)Etot * 32;
    float* sinv1 = ws + off; off += (size_t)n * 32;
    float* et2  = ws + off; off += (size_t)Etot;
    float* sinv2 = ws + off; off += (size_t)n;
    int* counts  = (int*)(ws + off); off += n;
    int* cursor  = (int*)(ws + off); off += n;
    int* offsets = (int*)(ws + off); off += n + 8;
    int* srcs    = (int*)(ws + off); off += Etot;
    float* es2 = es1;
    float* ed2 = ed1;

    // casts
    cast_f32_bf16<<<(n * 128 / 4 + 255) / 256, 256, 0, stream>>>(x, xb, n * 128 / 4);
    transpose_cast<<<(128 * 1024 + 255) / 256, 256, 0, stream>>>(W1, W1T, 128, 1024);
    transpose_cast<<<(1024 * 64 + 255) / 256, 256, 0, stream>>>(W2, W2T, 1024, 64);

    // CSR build
    hipMemsetAsync(counts, 0, 2 * (size_t)n * sizeof(int), stream);
    count_edges<<<(Etot + 255) / 256, 256, 0, stream>>>(ei, counts, E0, n);
    scan_excl<<<1, 1024, 0, stream>>>(counts, offsets, n);
    fill_edges<<<(Etot + 255) / 256, 256, 0, stream>>>(ei, offsets, cursor, srcs, E0, n);

    // layer 1 (es/ed fused into GEMM epilogue)
    gemm_mfma_attn<<<dim3((n + 63) / 64, 1024 / 64), 256, 0, stream>>>(
        xb, W1T, hb1, att_src1, att_dst1, es1, ed1, n, 1024, 128);
    stats1<<<n, 256, 0, stream>>>(es1, ed1, offsets, srcs, et1, sinv1, n);
    gather1<<<n, 256, 0, stream>>>(hb1, et1, sinv1, offsets, srcs, b1, hact, n);

    // layer 2
    gemm_mfma<<<dim3((n + 63) / 64, 64 / 64), 256, 0, stream>>>(hact, W2T, hb2, n, 64, 1024);
    attn_scores2<<<(n + 3) / 4, 256, 0, stream>>>(hb2, att_src2, att_dst2, es2, ed2, n);
    stats2<<<(n + 3) / 4, 256, 0, stream>>>(es2, ed2, offsets, srcs, et2, sinv2, n);
    gather2<<<(n + 3) / 4, 256, 0, stream>>>(hb2, et2, sinv2, offsets, srcs, b2, out, n);
}

// Round 6
// 238.140 us; speedup vs baseline: 1.6171x; 1.0824x over previous
//
#include <hip/hip_runtime.h>
#include <hip/hip_bf16.h>
#include <math.h>

typedef __attribute__((ext_vector_type(8))) short bf16x8;
typedef __attribute__((ext_vector_type(4))) float f32x4;
typedef __attribute__((ext_vector_type(8))) unsigned short u16x8;

__device__ inline float bf2f(unsigned short u) {
    union { float f; unsigned int i; } c; c.i = ((unsigned int)u) << 16; return c.f;
}
__device__ inline unsigned short f2bf(float f) {
    union { float f; unsigned int i; } c; c.f = f;
    unsigned int r = c.i + 0x7fffu + ((c.i >> 16) & 1u);
    return (unsigned short)(r >> 16);
}

// ---------------- casts ----------------
__global__ void cast_f32_bf16(const float* __restrict__ in, unsigned short* __restrict__ out,
                              int count4) {
    int i = blockIdx.x * blockDim.x + threadIdx.x;
    if (i >= count4) return;
    float4 v = *(const float4*)&in[(size_t)i * 4];
    ushort4 o;
    o.x = f2bf(v.x); o.y = f2bf(v.y); o.z = f2bf(v.z); o.w = f2bf(v.w);
    *(ushort4*)&out[(size_t)i * 4] = o;
}

// W [K][N] row-major f32 -> WT [N][K] bf16
__global__ void transpose_cast(const float* __restrict__ W, unsigned short* __restrict__ WT,
                               int K, int N) {
    int idx = blockIdx.x * blockDim.x + threadIdx.x;
    if (idx >= K * N) return;
    int nn = idx / K, kk = idx - nn * K;
    WT[idx] = f2bf(W[(size_t)kk * N + nn]);
}

// ---------------- MFMA GEMM (layer 1) + es/ed epilogue -------------------
__global__ __launch_bounds__(256) void gemm_mfma_attn(const unsigned short* __restrict__ A,
                                                      const unsigned short* __restrict__ BT,
                                                      unsigned short* __restrict__ C,
                                                      const float* __restrict__ asrc,
                                                      const float* __restrict__ adst,
                                                      float* __restrict__ es,
                                                      float* __restrict__ ed,
                                                      int M, int N, int K) {
    int tid = threadIdx.x;
    int wid = tid >> 6, lane = tid & 63;
    int wm = wid >> 1, wn = wid & 1;
    int m0 = blockIdx.x * 64 + wm * 32;
    int n0 = blockIdx.y * 64 + wn * 32;
    int lr = lane & 15;
    int q  = lane >> 4;
    int lk = q * 8;

    int ra0 = min(m0 + lr, M - 1);
    int ra1 = min(m0 + 16 + lr, M - 1);
    const unsigned short* pa0 = A + (size_t)ra0 * K + lk;
    const unsigned short* pa1 = A + (size_t)ra1 * K + lk;
    const unsigned short* pb0 = BT + (size_t)(n0 + lr) * K + lk;
    const unsigned short* pb1 = BT + (size_t)(n0 + 16 + lr) * K + lk;

    f32x4 acc00 = {0,0,0,0}, acc01 = {0,0,0,0}, acc10 = {0,0,0,0}, acc11 = {0,0,0,0};
    for (int k = 0; k < K; k += 64) {
        bf16x8 a0 = *(const bf16x8*)(pa0 + k);
        bf16x8 a1 = *(const bf16x8*)(pa1 + k);
        bf16x8 b0 = *(const bf16x8*)(pb0 + k);
        bf16x8 b1 = *(const bf16x8*)(pb1 + k);
        bf16x8 a0b = *(const bf16x8*)(pa0 + k + 32);
        bf16x8 a1b = *(const bf16x8*)(pa1 + k + 32);
        bf16x8 b0b = *(const bf16x8*)(pb0 + k + 32);
        bf16x8 b1b = *(const bf16x8*)(pb1 + k + 32);
        acc00 = __builtin_amdgcn_mfma_f32_16x16x32_bf16(a0, b0, acc00, 0, 0, 0);
        acc01 = __builtin_amdgcn_mfma_f32_16x16x32_bf16(a0, b1, acc01, 0, 0, 0);
        acc10 = __builtin_amdgcn_mfma_f32_16x16x32_bf16(a1, b0, acc10, 0, 0, 0);
        acc11 = __builtin_amdgcn_mfma_f32_16x16x32_bf16(a1, b1, acc11, 0, 0, 0);
        acc00 = __builtin_amdgcn_mfma_f32_16x16x32_bf16(a0b, b0b, acc00, 0, 0, 0);
        acc01 = __builtin_amdgcn_mfma_f32_16x16x32_bf16(a0b, b1b, acc01, 0, 0, 0);
        acc10 = __builtin_amdgcn_mfma_f32_16x16x32_bf16(a1b, b0b, acc10, 0, 0, 0);
        acc11 = __builtin_amdgcn_mfma_f32_16x16x32_bf16(a1b, b1b, acc11, 0, 0, 0);
    }
    int srow = q * 4;
    #pragma unroll
    for (int r = 0; r < 4; ++r) {
        int r0 = m0 + srow + r, r1 = m0 + 16 + srow + r;
        if (r0 < M) {
            C[(size_t)r0 * N + n0 + lr]      = f2bf(acc00[r]);
            C[(size_t)r0 * N + n0 + 16 + lr] = f2bf(acc01[r]);
        }
        if (r1 < M) {
            C[(size_t)r1 * N + n0 + lr]      = f2bf(acc10[r]);
            C[(size_t)r1 * N + n0 + 16 + lr] = f2bf(acc11[r]);
        }
    }
    int head = blockIdx.y * 2 + wn;
    float as_lo = asrc[head * 32 + lr], as_hi = asrc[head * 32 + 16 + lr];
    float ad_lo = adst[head * 32 + lr], ad_hi = adst[head * 32 + 16 + lr];
    #pragma unroll
    for (int X = 0; X < 2; ++X) {
        f32x4 ac0 = X ? acc10 : acc00;
        f32x4 ac1 = X ? acc11 : acc01;
        #pragma unroll
        for (int r = 0; r < 4; ++r) {
            float ps = ac0[r] * as_lo + ac1[r] * as_hi;
            float pd = ac0[r] * ad_lo + ac1[r] * ad_hi;
            #pragma unroll
            for (int msk = 1; msk < 16; msk <<= 1) {
                ps += __shfl_xor(ps, msk);
                pd += __shfl_xor(pd, msk);
            }
            int row = m0 + X * 16 + q * 4 + r;
            if (lr == 0 && row < M) {
                es[row * 32 + head] = ps;
                ed[row * 32 + head] = pd;
            }
        }
    }
}

// ---------------- MFMA GEMM plain (layer 2) ----------------
__global__ __launch_bounds__(256) void gemm_mfma(const unsigned short* __restrict__ A,
                                                 const unsigned short* __restrict__ BT,
                                                 unsigned short* __restrict__ C,
                                                 int M, int N, int K) {
    int tid = threadIdx.x;
    int wid = tid >> 6, lane = tid & 63;
    int wm = wid >> 1, wn = wid & 1;
    int m0 = blockIdx.x * 64 + wm * 32;
    int n0 = blockIdx.y * 64 + wn * 32;
    int lr = lane & 15;
    int lk = (lane >> 4) * 8;

    int ra0 = min(m0 + lr, M - 1);
    int ra1 = min(m0 + 16 + lr, M - 1);
    const unsigned short* pa0 = A + (size_t)ra0 * K + lk;
    const unsigned short* pa1 = A + (size_t)ra1 * K + lk;
    const unsigned short* pb0 = BT + (size_t)(n0 + lr) * K + lk;
    const unsigned short* pb1 = BT + (size_t)(n0 + 16 + lr) * K + lk;

    f32x4 acc00 = {0,0,0,0}, acc01 = {0,0,0,0}, acc10 = {0,0,0,0}, acc11 = {0,0,0,0};
    for (int k = 0; k < K; k += 64) {
        bf16x8 a0 = *(const bf16x8*)(pa0 + k);
        bf16x8 a1 = *(const bf16x8*)(pa1 + k);
        bf16x8 b0 = *(const bf16x8*)(pb0 + k);
        bf16x8 b1 = *(const bf16x8*)(pb1 + k);
        bf16x8 a0b = *(const bf16x8*)(pa0 + k + 32);
        bf16x8 a1b = *(const bf16x8*)(pa1 + k + 32);
        bf16x8 b0b = *(const bf16x8*)(pb0 + k + 32);
        bf16x8 b1b = *(const bf16x8*)(pb1 + k + 32);
        acc00 = __builtin_amdgcn_mfma_f32_16x16x32_bf16(a0, b0, acc00, 0, 0, 0);
        acc01 = __builtin_amdgcn_mfma_f32_16x16x32_bf16(a0, b1, acc01, 0, 0, 0);
        acc10 = __builtin_amdgcn_mfma_f32_16x16x32_bf16(a1, b0, acc10, 0, 0, 0);
        acc11 = __builtin_amdgcn_mfma_f32_16x16x32_bf16(a1, b1, acc11, 0, 0, 0);
        acc00 = __builtin_amdgcn_mfma_f32_16x16x32_bf16(a0b, b0b, acc00, 0, 0, 0);
        acc01 = __builtin_amdgcn_mfma_f32_16x16x32_bf16(a0b, b1b, acc01, 0, 0, 0);
        acc10 = __builtin_amdgcn_mfma_f32_16x16x32_bf16(a1b, b0b, acc10, 0, 0, 0);
        acc11 = __builtin_amdgcn_mfma_f32_16x16x32_bf16(a1b, b1b, acc11, 0, 0, 0);
    }
    int srow = (lane >> 4) * 4;
    #pragma unroll
    for (int r = 0; r < 4; ++r) {
        int r0 = m0 + srow + r, r1 = m0 + 16 + srow + r;
        if (r0 < M) {
            C[(size_t)r0 * N + n0 + lr]      = f2bf(acc00[r]);
            C[(size_t)r0 * N + n0 + 16 + lr] = f2bf(acc01[r]);
        }
        if (r1 < M) {
            C[(size_t)r1 * N + n0 + lr]      = f2bf(acc10[r]);
            C[(size_t)r1 * N + n0 + 16 + lr] = f2bf(acc11[r]);
        }
    }
}

// ---------------- CSR build ----------------
__global__ void count_edges(const int* __restrict__ ei, int* __restrict__ counts,
                            int E0, int n) {
    int e = blockIdx.x * blockDim.x + threadIdx.x;
    int Etot = E0 + n;
    if (e >= Etot) return;
    int dst = (e < E0) ? ei[E0 + e] : (e - E0);
    atomicAdd(&counts[dst], 1);
}

// wave-shuffle scan: 1024 thr = 16 waves; 3 barriers per 1024-chunk
__global__ void scan_excl(const int* __restrict__ counts, int* __restrict__ offsets, int n) {
    __shared__ int wpre[16];
    __shared__ int total_s;
    __shared__ int running_s;
    int tid = threadIdx.x, lane = tid & 63, w = tid >> 6;
    if (tid == 0) running_s = 0;
    __syncthreads();
    for (int base = 0; base < n; base += 1024) {
        int i = base + tid;
        int v = (i < n) ? counts[i] : 0;
        int incl = v;
        #pragma unroll
        for (int d = 1; d < 64; d <<= 1) {
            int t = __shfl_up(incl, d);
            if (lane >= d) incl += t;
        }
        if (lane == 63) wpre[w] = incl;
        __syncthreads();
        if (w == 0) {
            int s = (lane < 16) ? wpre[lane] : 0;
            int sc = s;
            #pragma unroll
            for (int d = 1; d < 16; d <<= 1) {
                int t = __shfl_up(sc, d);
                if (lane >= d) sc += t;
            }
            if (lane < 16) wpre[lane] = sc - s;   // exclusive wave prefix
            if (lane == 15) total_s = sc;
        }
        __syncthreads();
        int r = running_s;
        if (i < n) offsets[i] = r + wpre[w] + incl - v;
        __syncthreads();
        if (tid == 0) running_s = r + total_s;
        __syncthreads();
    }
    if (tid == 0) offsets[n] = running_s;
}

__global__ void fill_edges(const int* __restrict__ ei, const int* __restrict__ offsets,
                           int* __restrict__ cursor, int* __restrict__ srcs,
                           int E0, int n) {
    int e = blockIdx.x * blockDim.x + threadIdx.x;
    int Etot = E0 + n;
    if (e >= Etot) return;
    int src, dst;
    if (e < E0) { src = ei[e]; dst = ei[E0 + e]; }
    else        { src = dst = e - E0; }
    int pos = offsets[dst] + atomicAdd(&cursor[dst], 1);
    srcs[pos] = src;
}

// ---------------- Layer-1 stats: single sweep, no max, deferred norm -------
__global__ __launch_bounds__(256) void stats1(const float* __restrict__ es,
                                              const float* __restrict__ ed,
                                              const int* __restrict__ offsets,
                                              const int* __restrict__ srcs,
                                              float* __restrict__ et,
                                              float* __restrict__ sinv, int n) {
    int node = blockIdx.x;
    int tid = threadIdx.x;
    int h2 = tid & 31, j2 = tid >> 5;
    __shared__ float sed[32];
    __shared__ float red[4][32];
    int beg = offsets[node], end = offsets[node + 1];
    if (tid < 32) sed[tid] = ed[node * 32 + tid];
    __syncthreads();
    float edh = sed[h2];
    float ssum = 0.f;
    for (int e = beg + j2; e < end; e += 8) {
        int s = srcs[e];
        float ev = es[s * 32 + h2] + edh;
        ev = ev > 0.f ? ev : 0.2f * ev;
        float t = __expf(ev);
        et[(size_t)e * 32 + h2] = t;
        ssum += t;
    }
    ssum += __shfl_xor(ssum, 32);
    int w = tid >> 6;
    if ((tid & 63) < 32) red[w][h2] = ssum;
    __syncthreads();
    if (tid < 32) {
        float s = red[0][tid] + red[1][tid] + red[2][tid] + red[3][tid];
        sinv[node * 32 + tid] = 1.0f / (s + 1e-16f);
    }
}

// ---------------- Layer-1 gather: 16B/lane, 2 edges in flight -------------
__global__ __launch_bounds__(256) void gather1(const unsigned short* __restrict__ hb,
                                               const float* __restrict__ et,
                                               const float* __restrict__ sinv,
                                               const int* __restrict__ offsets,
                                               const int* __restrict__ srcs,
                                               const float* __restrict__ b1,
                                               unsigned short* __restrict__ out, int n) {
    int node = blockIdx.x;
    int tid = threadIdx.x;
    int ep = tid >> 7;              // edge parity 0/1
    int t2 = tid & 127;
    int head = t2 >> 2;             // 0..31
    int c8 = (t2 & 3) * 8;          // 8-channel quad
    int hoff = head * 32 + c8;
    int beg = offsets[node], end = offsets[node + 1];
    float a[8] = {0.f,0.f,0.f,0.f,0.f,0.f,0.f,0.f};
    int e = beg + ep;
    for (; e + 2 < end; e += 4) {
        int s0 = srcs[e], s1 = srcs[e + 2];
        float t0 = et[(size_t)e * 32 + head];
        float t1 = et[(size_t)(e + 2) * 32 + head];
        u16x8 h0 = *(const u16x8*)&hb[(size_t)s0 * 1024 + hoff];
        u16x8 h1 = *(const u16x8*)&hb[(size_t)s1 * 1024 + hoff];
        #pragma unroll
        for (int j = 0; j < 8; ++j) a[j] += t0 * bf2f(h0[j]) + t1 * bf2f(h1[j]);
    }
    if (e < end) {
        int s0 = srcs[e];
        float t0 = et[(size_t)e * 32 + head];
        u16x8 h0 = *(const u16x8*)&hb[(size_t)s0 * 1024 + hoff];
        #pragma unroll
        for (int j = 0; j < 8; ++j) a[j] += t0 * bf2f(h0[j]);
    }
    __shared__ float lds[128][9];
    if (ep == 1) {
        #pragma unroll
        for (int j = 0; j < 8; ++j) lds[t2][j] = a[j];
    }
    __syncthreads();
    if (ep == 0) {
        float si = sinv[node * 32 + head];
        float4 bl = *(const float4*)&b1[hoff];
        float4 bh = *(const float4*)&b1[hoff + 4];
        float bb[8] = {bl.x, bl.y, bl.z, bl.w, bh.x, bh.y, bh.z, bh.w};
        u16x8 o8;
        #pragma unroll
        for (int j = 0; j < 8; ++j) {
            float r = (a[j] + lds[t2][j]) * si + bb[j];
            r = r > 0.f ? r : expm1f(r);
            o8[j] = f2bf(r);
        }
        *(u16x8*)&out[(size_t)node * 1024 + hoff] = o8;
    }
}

// ---------------- Layer-2 attention scores from bf16 h2 ----------------
__global__ void attn_scores2(const unsigned short* __restrict__ hb2,
                             const float* __restrict__ asrc,
                             const float* __restrict__ adst,
                             float* __restrict__ es, float* __restrict__ ed, int n) {
    int node = blockIdx.x * (blockDim.x >> 6) + (threadIdx.x >> 6);
    int lane = threadIdx.x & 63;
    if (node >= n) return;
    float v = bf2f(hb2[(size_t)node * 64 + lane]);
    float s1 = v * asrc[lane];
    float s2 = v * adst[lane];
    #pragma unroll
    for (int o = 1; o < 64; o <<= 1) {
        s1 += __shfl_xor(s1, o);
        s2 += __shfl_xor(s2, o);
    }
    if (lane == 0) { es[node] = s1; ed[node] = s2; }
}

// ---------------- Layer-2 stats ----------------
__global__ void stats2(const float* __restrict__ es, const float* __restrict__ ed,
                       const int* __restrict__ offsets, const int* __restrict__ srcs,
                       float* __restrict__ et2, float* __restrict__ sinv2, int n) {
    int node = blockIdx.x * (blockDim.x >> 6) + (threadIdx.x >> 6);
    int lane = threadIdx.x & 63;
    if (node >= n) return;
    int beg = offsets[node], end = offsets[node + 1];
    float edv = ed[node];
    float ssum = 0.f;
    for (int e = beg + lane; e < end; e += 64) {
        float ev = es[srcs[e]] + edv;
        ev = ev > 0.f ? ev : 0.2f * ev;
        float t = __expf(ev);
        et2[e] = t;
        ssum += t;
    }
    #pragma unroll
    for (int o = 1; o < 64; o <<= 1) ssum += __shfl_xor(ssum, o);
    if (lane == 0) sinv2[node] = 1.0f / (ssum + 1e-16f);
}

// ---------------- Layer-2 gather: direct row loads, unroll x2 --------------
__global__ void gather2(const unsigned short* __restrict__ hb2,
                        const float* __restrict__ et2,
                        const float* __restrict__ sinv2,
                        const int* __restrict__ offsets, const int* __restrict__ srcs,
                        const float* __restrict__ b2, float* __restrict__ out, int n) {
    int node = blockIdx.x * (blockDim.x >> 6) + (threadIdx.x >> 6);
    int lane = threadIdx.x & 63;
    if (node >= n) return;
    int beg = offsets[node], end = offsets[node + 1];
    float acc = 0.f;
    int e = beg;
    for (; e + 1 < end; e += 2) {
        int s0 = srcs[e], s1 = srcs[e + 1];
        float t0 = et2[e], t1 = et2[e + 1];
        acc += t0 * bf2f(hb2[(size_t)s0 * 64 + lane])
             + t1 * bf2f(hb2[(size_t)s1 * 64 + lane]);
    }
    if (e < end) {
        acc += et2[e] * bf2f(hb2[(size_t)srcs[e] * 64 + lane]);
    }
    out[(size_t)node * 64 + lane] = acc * sinv2[node] + b2[lane];
}

// ---------------- launch ----------------
extern "C" void kernel_launch(void* const* d_in, const int* in_sizes, int n_in,
                              void* d_out, int out_size, void* d_ws, size_t ws_size,
                              hipStream_t stream) {
    const float* x        = (const float*)d_in[0];
    const int*   ei       = (const int*)d_in[1];
    const float* W1       = (const float*)d_in[2];
    const float* att_src1 = (const float*)d_in[3];
    const float* att_dst1 = (const float*)d_in[4];
    const float* b1       = (const float*)d_in[5];
    const float* W2       = (const float*)d_in[6];
    const float* att_src2 = (const float*)d_in[7];
    const float* att_dst2 = (const float*)d_in[8];
    const float* b2       = (const float*)d_in[9];
    float* out = (float*)d_out;

    int n  = in_sizes[0] / 128;   // 20000
    int E0 = in_sizes[1] / 2;     // 160000
    int Etot = E0 + n;

    float* ws = (float*)d_ws;
    size_t off = 0;
    unsigned short* hb1 = (unsigned short*)(ws + off); off += (size_t)n * 512;
    unsigned short* hact = (unsigned short*)(ws + off); off += (size_t)n * 512;
    unsigned short* hb2 = (unsigned short*)(ws + off); off += (size_t)n * 32;
    unsigned short* xb  = (unsigned short*)(ws + off); off += (size_t)n * 64;
    unsigned short* W1T = (unsigned short*)(ws + off); off += 1024 * 128 / 2;
    unsigned short* W2T = (unsigned short*)(ws + off); off += 64 * 1024 / 2;
    float* es1  = ws + off; off += (size_t)n * 32;
    float* ed1  = ws + off; off += (size_t)n * 32;
    float* et1  = ws + off; off += (size_t)Etot * 32;
    float* sinv1 = ws + off; off += (size_t)n * 32;
    float* et2  = ws + off; off += (size_t)Etot;
    float* sinv2 = ws + off; off += (size_t)n;
    int* counts  = (int*)(ws + off); off += n;
    int* cursor  = (int*)(ws + off); off += n;
    int* offsets = (int*)(ws + off); off += n + 8;
    int* srcs    = (int*)(ws + off); off += Etot;
    float* es2 = es1;
    float* ed2 = ed1;

    // casts
    cast_f32_bf16<<<(n * 128 / 4 + 255) / 256, 256, 0, stream>>>(x, xb, n * 128 / 4);
    transpose_cast<<<(128 * 1024 + 255) / 256, 256, 0, stream>>>(W1, W1T, 128, 1024);
    transpose_cast<<<(1024 * 64 + 255) / 256, 256, 0, stream>>>(W2, W2T, 1024, 64);

    // CSR build
    hipMemsetAsync(counts, 0, 2 * (size_t)n * sizeof(int), stream);
    count_edges<<<(Etot + 255) / 256, 256, 0, stream>>>(ei, counts, E0, n);
    scan_excl<<<1, 1024, 0, stream>>>(counts, offsets, n);
    fill_edges<<<(Etot + 255) / 256, 256, 0, stream>>>(ei, offsets, cursor, srcs, E0, n);

    // layer 1 (es/ed fused into GEMM epilogue)
    gemm_mfma_attn<<<dim3((n + 63) / 64, 1024 / 64), 256, 0, stream>>>(
        xb, W1T, hb1, att_src1, att_dst1, es1, ed1, n, 1024, 128);
    stats1<<<n, 256, 0, stream>>>(es1, ed1, offsets, srcs, et1, sinv1, n);
    gather1<<<n, 256, 0, stream>>>(hb1, et1, sinv1, offsets, srcs, b1, hact, n);

    // layer 2
    gemm_mfma<<<dim3((n + 63) / 64, 64 / 64), 256, 0, stream>>>(hact, W2T, hb2, n, 64, 1024);
    attn_scores2<<<(n + 3) / 4, 256, 0, stream>>>(hb2, att_src2, att_dst2, es2, ed2, n);
    stats2<<<(n + 3) / 4, 256, 0, stream>>>(es2, ed2, offsets, srcs, et2, sinv2, n);
    gather2<<<(n + 3) / 4, 256, 0, stream>>>(hb2, et2, sinv2, offsets, srcs, b2, out, n);
}

// Round 7
// 219.216 us; speedup vs baseline: 1.7567x; 1.0863x over previous
//
#include <hip/hip_runtime.h>
#include <hip/hip_bf16.h>
#include <math.h>

typedef __attribute__((ext_vector_type(8))) short bf16x8;
typedef __attribute__((ext_vector_type(4))) float f32x4;
typedef __attribute__((ext_vector_type(8))) unsigned short u16x8;

__device__ inline float bf2f(unsigned short u) {
    union { float f; unsigned int i; } c; c.i = ((unsigned int)u) << 16; return c.f;
}
__device__ inline unsigned short f2bf(float f) {
    union { float f; unsigned int i; } c; c.f = f;
    unsigned int r = c.i + 0x7fffu + ((c.i >> 16) & 1u);
    return (unsigned short)(r >> 16);
}

// ---------------- casts ----------------
__global__ void cast_f32_bf16(const float* __restrict__ in, unsigned short* __restrict__ out,
                              int count4) {
    int i = blockIdx.x * blockDim.x + threadIdx.x;
    if (i >= count4) return;
    float4 v = *(const float4*)&in[(size_t)i * 4];
    ushort4 o;
    o.x = f2bf(v.x); o.y = f2bf(v.y); o.z = f2bf(v.z); o.w = f2bf(v.w);
    *(ushort4*)&out[(size_t)i * 4] = o;
}

// W [K][N] row-major f32 -> WT [N][K] bf16
__global__ void transpose_cast(const float* __restrict__ W, unsigned short* __restrict__ WT,
                               int K, int N) {
    int idx = blockIdx.x * blockDim.x + threadIdx.x;
    if (idx >= K * N) return;
    int nn = idx / K, kk = idx - nn * K;
    WT[idx] = f2bf(W[(size_t)kk * N + nn]);
}

// ---------------- MFMA GEMM (layer 1) + es/ed epilogue -------------------
__global__ __launch_bounds__(256) void gemm_mfma_attn(const unsigned short* __restrict__ A,
                                                      const unsigned short* __restrict__ BT,
                                                      unsigned short* __restrict__ C,
                                                      const float* __restrict__ asrc,
                                                      const float* __restrict__ adst,
                                                      float* __restrict__ es,
                                                      float* __restrict__ ed,
                                                      int M, int N, int K) {
    int tid = threadIdx.x;
    int wid = tid >> 6, lane = tid & 63;
    int wm = wid >> 1, wn = wid & 1;
    int m0 = blockIdx.x * 64 + wm * 32;
    int n0 = blockIdx.y * 64 + wn * 32;
    int lr = lane & 15;
    int q  = lane >> 4;
    int lk = q * 8;

    int ra0 = min(m0 + lr, M - 1);
    int ra1 = min(m0 + 16 + lr, M - 1);
    const unsigned short* pa0 = A + (size_t)ra0 * K + lk;
    const unsigned short* pa1 = A + (size_t)ra1 * K + lk;
    const unsigned short* pb0 = BT + (size_t)(n0 + lr) * K + lk;
    const unsigned short* pb1 = BT + (size_t)(n0 + 16 + lr) * K + lk;

    f32x4 acc00 = {0,0,0,0}, acc01 = {0,0,0,0}, acc10 = {0,0,0,0}, acc11 = {0,0,0,0};
    for (int k = 0; k < K; k += 64) {
        bf16x8 a0 = *(const bf16x8*)(pa0 + k);
        bf16x8 a1 = *(const bf16x8*)(pa1 + k);
        bf16x8 b0 = *(const bf16x8*)(pb0 + k);
        bf16x8 b1 = *(const bf16x8*)(pb1 + k);
        bf16x8 a0b = *(const bf16x8*)(pa0 + k + 32);
        bf16x8 a1b = *(const bf16x8*)(pa1 + k + 32);
        bf16x8 b0b = *(const bf16x8*)(pb0 + k + 32);
        bf16x8 b1b = *(const bf16x8*)(pb1 + k + 32);
        acc00 = __builtin_amdgcn_mfma_f32_16x16x32_bf16(a0, b0, acc00, 0, 0, 0);
        acc01 = __builtin_amdgcn_mfma_f32_16x16x32_bf16(a0, b1, acc01, 0, 0, 0);
        acc10 = __builtin_amdgcn_mfma_f32_16x16x32_bf16(a1, b0, acc10, 0, 0, 0);
        acc11 = __builtin_amdgcn_mfma_f32_16x16x32_bf16(a1, b1, acc11, 0, 0, 0);
        acc00 = __builtin_amdgcn_mfma_f32_16x16x32_bf16(a0b, b0b, acc00, 0, 0, 0);
        acc01 = __builtin_amdgcn_mfma_f32_16x16x32_bf16(a0b, b1b, acc01, 0, 0, 0);
        acc10 = __builtin_amdgcn_mfma_f32_16x16x32_bf16(a1b, b0b, acc10, 0, 0, 0);
        acc11 = __builtin_amdgcn_mfma_f32_16x16x32_bf16(a1b, b1b, acc11, 0, 0, 0);
    }
    int srow = q * 4;
    #pragma unroll
    for (int r = 0; r < 4; ++r) {
        int r0 = m0 + srow + r, r1 = m0 + 16 + srow + r;
        if (r0 < M) {
            C[(size_t)r0 * N + n0 + lr]      = f2bf(acc00[r]);
            C[(size_t)r0 * N + n0 + 16 + lr] = f2bf(acc01[r]);
        }
        if (r1 < M) {
            C[(size_t)r1 * N + n0 + lr]      = f2bf(acc10[r]);
            C[(size_t)r1 * N + n0 + 16 + lr] = f2bf(acc11[r]);
        }
    }
    int head = blockIdx.y * 2 + wn;
    float as_lo = asrc[head * 32 + lr], as_hi = asrc[head * 32 + 16 + lr];
    float ad_lo = adst[head * 32 + lr], ad_hi = adst[head * 32 + 16 + lr];
    #pragma unroll
    for (int X = 0; X < 2; ++X) {
        f32x4 ac0 = X ? acc10 : acc00;
        f32x4 ac1 = X ? acc11 : acc01;
        #pragma unroll
        for (int r = 0; r < 4; ++r) {
            float ps = ac0[r] * as_lo + ac1[r] * as_hi;
            float pd = ac0[r] * ad_lo + ac1[r] * ad_hi;
            #pragma unroll
            for (int msk = 1; msk < 16; msk <<= 1) {
                ps += __shfl_xor(ps, msk);
                pd += __shfl_xor(pd, msk);
            }
            int row = m0 + X * 16 + q * 4 + r;
            if (lr == 0 && row < M) {
                es[row * 32 + head] = ps;
                ed[row * 32 + head] = pd;
            }
        }
    }
}

// ---------------- Layer-2 GEMM, k-split 4 waves + es2/ed2 epilogue --------
// C[M,64](bf16) = A[M,1024] @ BT[64,1024]^T. Block = 32 rows; wave w owns
// k in [w*256,(w+1)*256). LDS reduce; fused es2/ed2 row-dots. M % 32 == 0.
__global__ __launch_bounds__(256) void gemm2_fused(const unsigned short* __restrict__ A,
                                                   const unsigned short* __restrict__ BT,
                                                   unsigned short* __restrict__ C,
                                                   const float* __restrict__ asrc,
                                                   const float* __restrict__ adst,
                                                   float* __restrict__ es,
                                                   float* __restrict__ ed, int M) {
    const int K = 1024;
    int tid = threadIdx.x, wid = tid >> 6, lane = tid & 63;
    int m0 = blockIdx.x * 32;
    int lr = lane & 15, q = lane >> 4, lk = q * 8;
    int k0 = wid * 256;

    const unsigned short* pa0 = A + (size_t)(m0 + lr) * K + k0 + lk;
    const unsigned short* pa1 = A + (size_t)(m0 + 16 + lr) * K + k0 + lk;
    const unsigned short* pb0 = BT + (size_t)(0  + lr) * K + k0 + lk;
    const unsigned short* pb1 = BT + (size_t)(16 + lr) * K + k0 + lk;
    const unsigned short* pb2 = BT + (size_t)(32 + lr) * K + k0 + lk;
    const unsigned short* pb3 = BT + (size_t)(48 + lr) * K + k0 + lk;

    f32x4 acc[2][4] = {};
    for (int k = 0; k < 256; k += 64) {
        bf16x8 a0  = *(const bf16x8*)(pa0 + k);
        bf16x8 a1  = *(const bf16x8*)(pa1 + k);
        bf16x8 a0b = *(const bf16x8*)(pa0 + k + 32);
        bf16x8 a1b = *(const bf16x8*)(pa1 + k + 32);
        bf16x8 b0  = *(const bf16x8*)(pb0 + k);
        bf16x8 b0b = *(const bf16x8*)(pb0 + k + 32);
        acc[0][0] = __builtin_amdgcn_mfma_f32_16x16x32_bf16(a0,  b0,  acc[0][0], 0, 0, 0);
        acc[1][0] = __builtin_amdgcn_mfma_f32_16x16x32_bf16(a1,  b0,  acc[1][0], 0, 0, 0);
        acc[0][0] = __builtin_amdgcn_mfma_f32_16x16x32_bf16(a0b, b0b, acc[0][0], 0, 0, 0);
        acc[1][0] = __builtin_amdgcn_mfma_f32_16x16x32_bf16(a1b, b0b, acc[1][0], 0, 0, 0);
        bf16x8 b1  = *(const bf16x8*)(pb1 + k);
        bf16x8 b1b = *(const bf16x8*)(pb1 + k + 32);
        acc[0][1] = __builtin_amdgcn_mfma_f32_16x16x32_bf16(a0,  b1,  acc[0][1], 0, 0, 0);
        acc[1][1] = __builtin_amdgcn_mfma_f32_16x16x32_bf16(a1,  b1,  acc[1][1], 0, 0, 0);
        acc[0][1] = __builtin_amdgcn_mfma_f32_16x16x32_bf16(a0b, b1b, acc[0][1], 0, 0, 0);
        acc[1][1] = __builtin_amdgcn_mfma_f32_16x16x32_bf16(a1b, b1b, acc[1][1], 0, 0, 0);
        bf16x8 b2  = *(const bf16x8*)(pb2 + k);
        bf16x8 b2b = *(const bf16x8*)(pb2 + k + 32);
        acc[0][2] = __builtin_amdgcn_mfma_f32_16x16x32_bf16(a0,  b2,  acc[0][2], 0, 0, 0);
        acc[1][2] = __builtin_amdgcn_mfma_f32_16x16x32_bf16(a1,  b2,  acc[1][2], 0, 0, 0);
        acc[0][2] = __builtin_amdgcn_mfma_f32_16x16x32_bf16(a0b, b2b, acc[0][2], 0, 0, 0);
        acc[1][2] = __builtin_amdgcn_mfma_f32_16x16x32_bf16(a1b, b2b, acc[1][2], 0, 0, 0);
        bf16x8 b3  = *(const bf16x8*)(pb3 + k);
        bf16x8 b3b = *(const bf16x8*)(pb3 + k + 32);
        acc[0][3] = __builtin_amdgcn_mfma_f32_16x16x32_bf16(a0,  b3,  acc[0][3], 0, 0, 0);
        acc[1][3] = __builtin_amdgcn_mfma_f32_16x16x32_bf16(a1,  b3,  acc[1][3], 0, 0, 0);
        acc[0][3] = __builtin_amdgcn_mfma_f32_16x16x32_bf16(a0b, b3b, acc[0][3], 0, 0, 0);
        acc[1][3] = __builtin_amdgcn_mfma_f32_16x16x32_bf16(a1b, b3b, acc[1][3], 0, 0, 0);
    }
    __shared__ float red[4][32][64];
    #pragma unroll
    for (int rf = 0; rf < 2; ++rf)
        #pragma unroll
        for (int cf = 0; cf < 4; ++cf)
            #pragma unroll
            for (int i = 0; i < 4; ++i)
                red[wid][rf * 16 + q * 4 + i][cf * 16 + lr] = acc[rf][cf][i];
    __syncthreads();
    int r = tid >> 3, c0 = (tid & 7) * 8;
    float v[8];
    #pragma unroll
    for (int j = 0; j < 8; ++j)
        v[j] = red[0][r][c0 + j] + red[1][r][c0 + j] + red[2][r][c0 + j] + red[3][r][c0 + j];
    u16x8 o8;
    float ps = 0.f, pd = 0.f;
    #pragma unroll
    for (int j = 0; j < 8; ++j) {
        o8[j] = f2bf(v[j]);
        ps += v[j] * asrc[c0 + j];
        pd += v[j] * adst[c0 + j];
    }
    int row = m0 + r;
    *(u16x8*)&C[(size_t)row * 64 + c0] = o8;
    #pragma unroll
    for (int msk = 1; msk < 8; msk <<= 1) {
        ps += __shfl_xor(ps, msk);
        pd += __shfl_xor(pd, msk);
    }
    if ((tid & 7) == 0) { es[row] = ps; ed[row] = pd; }
}

// ---------------- CSR build ----------------
__global__ void count_edges(const int* __restrict__ ei, int* __restrict__ counts,
                            int E0, int n) {
    int e = blockIdx.x * blockDim.x + threadIdx.x;
    int Etot = E0 + n;
    if (e >= Etot) return;
    int dst = (e < E0) ? ei[E0 + e] : (e - E0);
    atomicAdd(&counts[dst], 1);
}

// wave-shuffle scan: 1024 thr = 16 waves; 3 barriers per 1024-chunk
__global__ void scan_excl(const int* __restrict__ counts, int* __restrict__ offsets, int n) {
    __shared__ int wpre[16];
    __shared__ int total_s;
    __shared__ int running_s;
    int tid = threadIdx.x, lane = tid & 63, w = tid >> 6;
    if (tid == 0) running_s = 0;
    __syncthreads();
    for (int base = 0; base < n; base += 1024) {
        int i = base + tid;
        int v = (i < n) ? counts[i] : 0;
        int incl = v;
        #pragma unroll
        for (int d = 1; d < 64; d <<= 1) {
            int t = __shfl_up(incl, d);
            if (lane >= d) incl += t;
        }
        if (lane == 63) wpre[w] = incl;
        __syncthreads();
        if (w == 0) {
            int s = (lane < 16) ? wpre[lane] : 0;
            int sc = s;
            #pragma unroll
            for (int d = 1; d < 16; d <<= 1) {
                int t = __shfl_up(sc, d);
                if (lane >= d) sc += t;
            }
            if (lane < 16) wpre[lane] = sc - s;
            if (lane == 15) total_s = sc;
        }
        __syncthreads();
        int r = running_s;
        if (i < n) offsets[i] = r + wpre[w] + incl - v;
        __syncthreads();
        if (tid == 0) running_s = r + total_s;
        __syncthreads();
    }
    if (tid == 0) offsets[n] = running_s;
}

__global__ void fill_edges(const int* __restrict__ ei, const int* __restrict__ offsets,
                           int* __restrict__ cursor, int* __restrict__ srcs,
                           int E0, int n) {
    int e = blockIdx.x * blockDim.x + threadIdx.x;
    int Etot = E0 + n;
    if (e >= Etot) return;
    int src, dst;
    if (e < E0) { src = ei[e]; dst = ei[E0 + e]; }
    else        { src = dst = e - E0; }
    int pos = offsets[dst] + atomicAdd(&cursor[dst], 1);
    srcs[pos] = src;
}

// ---------------- Layer-1 stats: single sweep, no max, deferred norm -------
__global__ __launch_bounds__(256) void stats1(const float* __restrict__ es,
                                              const float* __restrict__ ed,
                                              const int* __restrict__ offsets,
                                              const int* __restrict__ srcs,
                                              float* __restrict__ et,
                                              float* __restrict__ sinv, int n) {
    int node = blockIdx.x;
    int tid = threadIdx.x;
    int h2 = tid & 31, j2 = tid >> 5;
    __shared__ float sed[32];
    __shared__ float red[4][32];
    int beg = offsets[node], end = offsets[node + 1];
    if (tid < 32) sed[tid] = ed[node * 32 + tid];
    __syncthreads();
    float edh = sed[h2];
    float ssum = 0.f;
    for (int e = beg + j2; e < end; e += 8) {
        int s = srcs[e];
        float ev = es[s * 32 + h2] + edh;
        ev = ev > 0.f ? ev : 0.2f * ev;
        float t = __expf(ev);
        et[(size_t)e * 32 + h2] = t;
        ssum += t;
    }
    ssum += __shfl_xor(ssum, 32);
    int w = tid >> 6;
    if ((tid & 63) < 32) red[w][h2] = ssum;
    __syncthreads();
    if (tid < 32) {
        float s = red[0][tid] + red[1][tid] + red[2][tid] + red[3][tid];
        sinv[node * 32 + tid] = 1.0f / (s + 1e-16f);
    }
}

// ---------------- Layer-1 gather: 16B/lane, 2 edges in flight -------------
__global__ __launch_bounds__(256) void gather1(const unsigned short* __restrict__ hb,
                                               const float* __restrict__ et,
                                               const float* __restrict__ sinv,
                                               const int* __restrict__ offsets,
                                               const int* __restrict__ srcs,
                                               const float* __restrict__ b1,
                                               unsigned short* __restrict__ out, int n) {
    int node = blockIdx.x;
    int tid = threadIdx.x;
    int ep = tid >> 7;              // edge parity 0/1
    int t2 = tid & 127;
    int head = t2 >> 2;             // 0..31
    int c8 = (t2 & 3) * 8;          // 8-channel quad
    int hoff = head * 32 + c8;
    int beg = offsets[node], end = offsets[node + 1];
    float a[8] = {0.f,0.f,0.f,0.f,0.f,0.f,0.f,0.f};
    int e = beg + ep;
    for (; e + 2 < end; e += 4) {
        int s0 = srcs[e], s1 = srcs[e + 2];
        float t0 = et[(size_t)e * 32 + head];
        float t1 = et[(size_t)(e + 2) * 32 + head];
        u16x8 h0 = *(const u16x8*)&hb[(size_t)s0 * 1024 + hoff];
        u16x8 h1 = *(const u16x8*)&hb[(size_t)s1 * 1024 + hoff];
        #pragma unroll
        for (int j = 0; j < 8; ++j) a[j] += t0 * bf2f(h0[j]) + t1 * bf2f(h1[j]);
    }
    if (e < end) {
        int s0 = srcs[e];
        float t0 = et[(size_t)e * 32 + head];
        u16x8 h0 = *(const u16x8*)&hb[(size_t)s0 * 1024 + hoff];
        #pragma unroll
        for (int j = 0; j < 8; ++j) a[j] += t0 * bf2f(h0[j]);
    }
    __shared__ float lds[128][9];
    if (ep == 1) {
        #pragma unroll
        for (int j = 0; j < 8; ++j) lds[t2][j] = a[j];
    }
    __syncthreads();
    if (ep == 0) {
        float si = sinv[node * 32 + head];
        float4 bl = *(const float4*)&b1[hoff];
        float4 bh = *(const float4*)&b1[hoff + 4];
        float bb[8] = {bl.x, bl.y, bl.z, bl.w, bh.x, bh.y, bh.z, bh.w};
        u16x8 o8;
        #pragma unroll
        for (int j = 0; j < 8; ++j) {
            float r = (a[j] + lds[t2][j]) * si + bb[j];
            r = r > 0.f ? r : expm1f(r);
            o8[j] = f2bf(r);
        }
        *(u16x8*)&out[(size_t)node * 1024 + hoff] = o8;
    }
}

// ---------------- Layer-2 stats ----------------
__global__ void stats2(const float* __restrict__ es, const float* __restrict__ ed,
                       const int* __restrict__ offsets, const int* __restrict__ srcs,
                       float* __restrict__ et2, float* __restrict__ sinv2, int n) {
    int node = blockIdx.x * (blockDim.x >> 6) + (threadIdx.x >> 6);
    int lane = threadIdx.x & 63;
    if (node >= n) return;
    int beg = offsets[node], end = offsets[node + 1];
    float edv = ed[node];
    float ssum = 0.f;
    for (int e = beg + lane; e < end; e += 64) {
        float ev = es[srcs[e]] + edv;
        ev = ev > 0.f ? ev : 0.2f * ev;
        float t = __expf(ev);
        et2[e] = t;
        ssum += t;
    }
    #pragma unroll
    for (int o = 1; o < 64; o <<= 1) ssum += __shfl_xor(ssum, o);
    if (lane == 0) sinv2[node] = 1.0f / (ssum + 1e-16f);
}

// ---------------- Layer-2 gather: direct row loads, unroll x4 --------------
__global__ void gather2(const unsigned short* __restrict__ hb2,
                        const float* __restrict__ et2,
                        const float* __restrict__ sinv2,
                        const int* __restrict__ offsets, const int* __restrict__ srcs,
                        const float* __restrict__ b2, float* __restrict__ out, int n) {
    int node = blockIdx.x * (blockDim.x >> 6) + (threadIdx.x >> 6);
    int lane = threadIdx.x & 63;
    if (node >= n) return;
    int beg = offsets[node], end = offsets[node + 1];
    float acc = 0.f;
    int e = beg;
    for (; e + 3 < end; e += 4) {
        int s0 = srcs[e], s1 = srcs[e + 1], s2 = srcs[e + 2], s3 = srcs[e + 3];
        float t0 = et2[e], t1 = et2[e + 1], t2 = et2[e + 2], t3 = et2[e + 3];
        acc += t0 * bf2f(hb2[(size_t)s0 * 64 + lane])
             + t1 * bf2f(hb2[(size_t)s1 * 64 + lane])
             + t2 * bf2f(hb2[(size_t)s2 * 64 + lane])
             + t3 * bf2f(hb2[(size_t)s3 * 64 + lane]);
    }
    for (; e < end; ++e) {
        acc += et2[e] * bf2f(hb2[(size_t)srcs[e] * 64 + lane]);
    }
    out[(size_t)node * 64 + lane] = acc * sinv2[node] + b2[lane];
}

// ---------------- launch ----------------
extern "C" void kernel_launch(void* const* d_in, const int* in_sizes, int n_in,
                              void* d_out, int out_size, void* d_ws, size_t ws_size,
                              hipStream_t stream) {
    const float* x        = (const float*)d_in[0];
    const int*   ei       = (const int*)d_in[1];
    const float* W1       = (const float*)d_in[2];
    const float* att_src1 = (const float*)d_in[3];
    const float* att_dst1 = (const float*)d_in[4];
    const float* b1       = (const float*)d_in[5];
    const float* W2       = (const float*)d_in[6];
    const float* att_src2 = (const float*)d_in[7];
    const float* att_dst2 = (const float*)d_in[8];
    const float* b2       = (const float*)d_in[9];
    float* out = (float*)d_out;

    int n  = in_sizes[0] / 128;   // 20000
    int E0 = in_sizes[1] / 2;     // 160000
    int Etot = E0 + n;

    float* ws = (float*)d_ws;
    size_t off = 0;
    unsigned short* hb1 = (unsigned short*)(ws + off); off += (size_t)n * 512;
    unsigned short* hact = (unsigned short*)(ws + off); off += (size_t)n * 512;
    unsigned short* hb2 = (unsigned short*)(ws + off); off += (size_t)n * 32;
    unsigned short* xb  = (unsigned short*)(ws + off); off += (size_t)n * 64;
    unsigned short* W1T = (unsigned short*)(ws + off); off += 1024 * 128 / 2;
    unsigned short* W2T = (unsigned short*)(ws + off); off += 64 * 1024 / 2;
    float* es1  = ws + off; off += (size_t)n * 32;
    float* ed1  = ws + off; off += (size_t)n * 32;
    float* et1  = ws + off; off += (size_t)Etot * 32;
    float* sinv1 = ws + off; off += (size_t)n * 32;
    float* et2  = ws + off; off += (size_t)Etot;
    float* sinv2 = ws + off; off += (size_t)n;
    int* counts  = (int*)(ws + off); off += n;
    int* cursor  = (int*)(ws + off); off += n;
    int* offsets = (int*)(ws + off); off += n + 8;
    int* srcs    = (int*)(ws + off); off += Etot;
    float* es2 = es1;
    float* ed2 = ed1;

    // casts
    cast_f32_bf16<<<(n * 128 / 4 + 255) / 256, 256, 0, stream>>>(x, xb, n * 128 / 4);
    transpose_cast<<<(128 * 1024 + 255) / 256, 256, 0, stream>>>(W1, W1T, 128, 1024);
    transpose_cast<<<(1024 * 64 + 255) / 256, 256, 0, stream>>>(W2, W2T, 1024, 64);

    // CSR build
    hipMemsetAsync(counts, 0, 2 * (size_t)n * sizeof(int), stream);
    count_edges<<<(Etot + 255) / 256, 256, 0, stream>>>(ei, counts, E0, n);
    scan_excl<<<1, 1024, 0, stream>>>(counts, offsets, n);
    fill_edges<<<(Etot + 255) / 256, 256, 0, stream>>>(ei, offsets, cursor, srcs, E0, n);

    // layer 1 (es/ed fused into GEMM epilogue)
    gemm_mfma_attn<<<dim3((n + 63) / 64, 1024 / 64), 256, 0, stream>>>(
        xb, W1T, hb1, att_src1, att_dst1, es1, ed1, n, 1024, 128);
    stats1<<<n, 256, 0, stream>>>(es1, ed1, offsets, srcs, et1, sinv1, n);
    gather1<<<n, 256, 0, stream>>>(hb1, et1, sinv1, offsets, srcs, b1, hact, n);

    // layer 2 (h2 GEMM + es2/ed2 fused; k-split for parallelism)
    gemm2_fused<<<n / 32, 256, 0, stream>>>(hact, W2T, hb2, att_src2, att_dst2, es2, ed2, n);
    stats2<<<(n + 3) / 4, 256, 0, stream>>>(es2, ed2, offsets, srcs, et2, sinv2, n);
    gather2<<<(n + 3) / 4, 256, 0, stream>>>(hb2, et2, sinv2, offsets, srcs, b2, out, n);
}